// Round 6
// baseline (2164.918 us; speedup 1.0000x reference)
//
#include <hip/hip_runtime.h>

// ---------------------------------------------------------------------------
// MultiHead_BlockAttention: out[b,s,h*512+d] = softmax(Q Kt) V  per (h,b)
//   Q = x@wq, K = x@wk, V = x@wv ; head h = cols [h*512,(h+1)*512)
// Trick: logits = X (Wq Wk^T) X^T  -> precompute M' = Wk Wq^T per head.
// Precision: bf16 hi/lo split (3 MFMAs) on the logit path; plain bf16 for V/P.
// R1: T/logits -> gemm256 (256x256, 8 waves, dbuf, 2-phase). 551us.
// R3: PV and VT moved to gemm256 too. 513us.
// R4: intra-step barriers REGRESSED (530us). R5: SGB pinning NULL (517us).
// R6: split gemm256 -> SINGLE-buffer (64KiB) + __launch_bounds__(512,4):
//     2 blocks/CU. The 1-block/CU dbuf variant serialized {stage|ds|MFMA}
//     across the whole CU at every barrier (8250 cyc/K-step vs 3725 MFMA
//     floor). Cross-block overlap (m114) covers the exposed stage; grid 512
//     becomes fully co-resident (1 round, no tail).
// ---------------------------------------------------------------------------

typedef unsigned short u16;
typedef __bf16 bf16x8 __attribute__((ext_vector_type(8)));
typedef unsigned short u16x4 __attribute__((ext_vector_type(4)));
typedef unsigned short u16x8s __attribute__((ext_vector_type(8)));
typedef float f32x4 __attribute__((ext_vector_type(4)));

typedef __attribute__((address_space(1))) void gvoid_t;
typedef __attribute__((address_space(3))) void svoid_t;

__device__ __forceinline__ u16 f2bf(float f) {
  unsigned u = __float_as_uint(f);
  u = (u + 0x7fffu + ((u >> 16) & 1u)) >> 16;  // RTN-even
  return (u16)u;
}
__device__ __forceinline__ float bf2f(u16 h) {
  return __uint_as_float(((unsigned)h) << 16);
}

__device__ __forceinline__ f32x4 mfma16(bf16x8 a, bf16x8 b, f32x4 c) {
  return __builtin_amdgcn_mfma_f32_16x16x32_bf16(a, b, c, 0, 0, 0);
}

// ---------------- prep: fp32 -> bf16 hi/lo split (same layout) -------------
__global__ __launch_bounds__(256) void split_hl_kernel(
    const float* __restrict__ in, u16* __restrict__ hi, u16* __restrict__ lo,
    int n4) {
  int i = blockIdx.x * 256 + threadIdx.x;
  if (i >= n4) return;
  float4 v = ((const float4*)in)[i];
  float vv[4] = {v.x, v.y, v.z, v.w};
  u16x4 h, l;
#pragma unroll
  for (int j = 0; j < 4; ++j) {
    u16 hh = f2bf(vv[j]);
    h[j] = hh;
    l[j] = f2bf(vv[j] - bf2f(hh));
  }
  ((u16x4*)hi)[i] = h;
  ((u16x4*)lo)[i] = l;
}

// ---------------- prep: transpose [512,4096] -> [4096,512] + split ---------
__global__ __launch_bounds__(256) void transpose_split_w(
    const float* __restrict__ in, u16* __restrict__ hi, u16* __restrict__ lo) {
  __shared__ float t[32][33];
  int d0 = blockIdx.x * 32, f0 = blockIdx.y * 32;
  int tx = threadIdx.x, ty = threadIdx.y;  // blockDim = (32,8)
#pragma unroll
  for (int r = 0; r < 4; ++r)
    t[ty + r * 8][tx] = in[(size_t)(f0 + ty + r * 8) * 4096 + d0 + tx];
  __syncthreads();
#pragma unroll
  for (int r = 0; r < 4; ++r) {
    float v = t[tx][ty + r * 8];  // = in[f0+tx][d0+ty+r*8]
    int d = d0 + ty + r * 8, f = f0 + tx;
    u16 h = f2bf(v);
    size_t idx = (size_t)d * 512 + f;
    hi[idx] = h;
    lo[idx] = f2bf(v - bf2f(h));
  }
}

// ---------------- shared LDS swizzle helpers -------------------------------
// LDS tiles [rows][32 k] bf16, XOR-swizzled at 16B-chunk granularity:
//   chunk (m,cq) stored at chunk col c' = cq ^ ((m>>1)&3)  (involution)
// so frag ds_read_b128 is <=2-way bank conflicted (free) AND staging stays
// compatible with global_load_lds's "base + lane*16" placement rule.
__device__ __forceinline__ bf16x8 ldsfrag(const u16* tile, int row, int quad) {
  int c = quad ^ ((row >> 1) & 3);
  return *(const bf16x8*)(tile + row * 32 + c * 8);
}

// ---------------- GEMM core (legacy 128x128): C[m][n] = sum_k A[m][k]B[n][k]
// 128x128 tile, BK=32, 256 threads (4 waves, each 64x64 = 4x4 frags of 16x16).
__device__ __forceinline__ void stage_tile(u16* ldsTile, const u16* g0, int ld,
                                           int wave, int lane) {
#pragma unroll
  for (int r = 0; r < 2; ++r) {
    int p = r * 256 + wave * 64 + lane;          // LDS chunk position
    int m = p >> 2;
    int cq = (p & 3) ^ ((m >> 1) & 3);           // global chunk col
    const u16* g = g0 + (size_t)m * ld + cq * 8;
    u16* l = ldsTile + (size_t)(r * 256 + wave * 64) * 8;  // wave-uniform
    __builtin_amdgcn_global_load_lds((gvoid_t*)g, (svoid_t*)l, 16, 0, 0);
  }
}

// OMODE: 0 = fp32 to C0 ; 1 = bf16 to C0 ; 2 = hi/lo bf16 to C0/C1
template <int SPLIT, int OMODE>
__global__ __launch_bounds__(256, 2) void gemm_bt(
    const u16* __restrict__ Ah, const u16* __restrict__ Al,
    const u16* __restrict__ Bh, const u16* __restrict__ Bl,
    void* __restrict__ C0, void* __restrict__ C1, int lda, int ldb, int ldc,
    int K, size_t aH, size_t aB, size_t bH, size_t bB, size_t cH, size_t cB) {
  __shared__ __align__(16) u16 lds[(SPLIT ? 4 : 2) * 4096];
  u16* lAh = lds;
  u16* lAl = SPLIT ? (lds + 4096) : lds;
  u16* lBh = lds + (SPLIT ? 8192 : 4096);
  u16* lBl = SPLIT ? (lds + 12288) : lds;

  const int zh = blockIdx.z >> 4, zb = blockIdx.z & 15;
  Ah += zh * aH + zb * aB;
  Al += zh * aH + zb * aB;
  Bh += zh * bH + zb * bB;
  Bl += zh * bH + zb * bB;
  const size_t cOff = zh * cH + zb * cB;

  const int m0 = blockIdx.y * 128, n0 = blockIdx.x * 128;
  const int tid = threadIdx.x;
  const int wave = tid >> 6, lane = tid & 63;
  const int quad = lane >> 4, l16 = lane & 15;
  const int wm = (wave >> 1) * 64, wn = (wave & 1) * 64;

  f32x4 acc[4][4] = {};

  for (int k0 = 0; k0 < K; k0 += 32) {
    stage_tile(lAh, Ah + (size_t)m0 * lda + k0, lda, wave, lane);
    if (SPLIT) stage_tile(lAl, Al + (size_t)m0 * lda + k0, lda, wave, lane);
    stage_tile(lBh, Bh + (size_t)n0 * ldb + k0, ldb, wave, lane);
    if (SPLIT) stage_tile(lBl, Bl + (size_t)n0 * ldb + k0, ldb, wave, lane);
    __syncthreads();

    bf16x8 a_h[4], a_l[4], b_h[4], b_l[4];
#pragma unroll
    for (int i = 0; i < 4; ++i) {
      a_h[i] = ldsfrag(lAh, wm + i * 16 + l16, quad);
      b_h[i] = ldsfrag(lBh, wn + i * 16 + l16, quad);
      if (SPLIT) {
        a_l[i] = ldsfrag(lAl, wm + i * 16 + l16, quad);
        b_l[i] = ldsfrag(lBl, wn + i * 16 + l16, quad);
      }
    }
#pragma unroll
    for (int i = 0; i < 4; ++i)
#pragma unroll
      for (int j = 0; j < 4; ++j) {
        acc[i][j] = mfma16(a_h[i], b_h[j], acc[i][j]);
        if (SPLIT) {
          acc[i][j] = mfma16(a_h[i], b_l[j], acc[i][j]);
          acc[i][j] = mfma16(a_l[i], b_h[j], acc[i][j]);
        }
      }
    __syncthreads();
  }

  // epilogue: C/D layout col = lane&15, row = quad*4 + reg (m89/m91 verified)
#pragma unroll
  for (int i = 0; i < 4; ++i) {
#pragma unroll
    for (int j = 0; j < 4; ++j) {
      int col = n0 + wn + j * 16 + l16;
#pragma unroll
      for (int r = 0; r < 4; ++r) {
        int row = m0 + wm + i * 16 + quad * 4 + r;
        size_t idx = cOff + (size_t)row * ldc + col;
        float v = acc[i][j][r];
        if (OMODE == 0) {
          ((float*)C0)[idx] = v;
        } else if (OMODE == 1) {
          ((u16*)C0)[idx] = f2bf(v);
        } else {
          u16 h = f2bf(v);
          ((u16*)C0)[idx] = h;
          ((u16*)C1)[idx] = f2bf(v - bf2f(h));
        }
      }
    }
  }
}

// ---------------- GEMM core (256x256, 8 waves) -----------------------------
// 256x256 tile, BK=32, 512 threads. Wave w = (w>>2, w&3) owns a 128x64
// sub-tile = acc[8][4] of 16x16 frags.
// DBUF=1 (non-split): double-buffered 2-phase pipeline, 64KiB LDS, one
//   __syncthreads() per K-step after compute (prefetch hides under MFMAs).
// DBUF=0 (split): SINGLE buffer, 64KiB LDS -> 2 blocks/CU. gemm_bt-style
//   {stage, barrier, compute, barrier}; the exposed stage latency is covered
//   by the co-resident block's compute (cross-block overlap), which the
//   1-block/CU dbuf variant could not get.
// __launch_bounds__(512,4) caps VGPR at 128 to guarantee 2 blocks/CU.
__device__ __forceinline__ void stage256(u16* tile, const u16* g0, int ld,
                                         int tid) {
  const int wave = tid >> 6;
#pragma unroll
  for (int r = 0; r < 2; ++r) {
    int p = r * 512 + tid;                        // chunk index 0..1023
    int m = p >> 2;                               // row 0..255
    int cq = (p & 3) ^ ((m >> 1) & 3);            // global chunk col
    const u16* g = g0 + (size_t)m * ld + cq * 8;
    u16* l = tile + (size_t)(r * 512 + wave * 64) * 8;  // wave-uniform base
    __builtin_amdgcn_global_load_lds((gvoid_t*)g, (svoid_t*)l, 16, 0, 0);
  }
}

template <int SPLIT>
__device__ __forceinline__ void stage_all256(u16* buf, const u16* Ah,
                                             const u16* Al, const u16* Bh,
                                             const u16* Bl, int lda, int ldb,
                                             int m0, int n0, int k0, int tid) {
  stage256(buf, Ah + (size_t)m0 * lda + k0, lda, tid);
  if (SPLIT) stage256(buf + 8192, Al + (size_t)m0 * lda + k0, lda, tid);
  stage256(buf + (SPLIT ? 16384 : 8192), Bh + (size_t)n0 * ldb + k0, ldb, tid);
  if (SPLIT) stage256(buf + 24576, Bl + (size_t)n0 * ldb + k0, ldb, tid);
}

template <int SPLIT, int OMODE, int DBUF>
__global__ __launch_bounds__(512, 4) void gemm256(
    const u16* __restrict__ Ah, const u16* __restrict__ Al,
    const u16* __restrict__ Bh, const u16* __restrict__ Bl,
    void* __restrict__ C0, void* __restrict__ C1, int lda, int ldb, int ldc,
    int K, size_t aH, size_t aB, size_t bH, size_t bB, size_t cH, size_t cB) {
  constexpr int BUF = (SPLIT ? 4 : 2) * 8192;     // u16 per buffer
  __shared__ __align__(16) u16 lds[(DBUF ? 2 : 1) * BUF];

  // ---- bijective XCD swizzle: XCD k gets contiguous work chunk k ----
  const int gx = gridDim.x, gy = gridDim.y;
  const int nb = gx * gy * (int)gridDim.z;
  int orig = blockIdx.x + gx * (blockIdx.y + gy * blockIdx.z);
  int swz = orig;
  if ((nb & 7) == 0) swz = (orig & 7) * (nb >> 3) + (orig >> 3);
  const int bx = swz % gx;
  const int byz = swz / gx;
  const int by = byz % gy;
  const int bz = byz / gy;

  const int zh = bz >> 4, zb = bz & 15;
  Ah += zh * aH + zb * aB;
  Al += zh * aH + zb * aB;
  Bh += zh * bH + zb * bB;
  Bl += zh * bH + zb * bB;
  const size_t cOff = zh * cH + zb * cB;

  const int m0 = by * 256, n0 = bx * 256;
  const int tid = threadIdx.x;
  const int wave = tid >> 6, lane = tid & 63;
  const int quad = lane >> 4, l16 = lane & 15;
  const int wm = (wave >> 2) * 128, wn = (wave & 3) * 64;

  f32x4 acc[8][4] = {};

  int cur = 0;
  if (DBUF) {
    // prologue: stage tile 0 into buffer 0; __syncthreads drains vmcnt
    stage_all256<SPLIT>(lds, Ah, Al, Bh, Bl, lda, ldb, m0, n0, 0, tid);
    __syncthreads();
  }

  for (int k0 = 0; k0 < K; k0 += 32) {
    if (DBUF) {
      // issue next tile's loads into the other buffer (overlap with compute)
      if (k0 + 32 < K)
        stage_all256<SPLIT>(lds + (cur ^ 1) * BUF, Ah, Al, Bh, Bl, lda, ldb,
                            m0, n0, k0 + 32, tid);
    } else {
      stage_all256<SPLIT>(lds, Ah, Al, Bh, Bl, lda, ldb, m0, n0, k0, tid);
      __syncthreads();  // vmcnt(0) drain + barrier: tile ready
    }

    u16* buf = lds + (DBUF ? cur * BUF : 0);
    u16* lA_h = buf;
    u16* lA_l = buf + 8192;
    u16* lB_h = buf + (SPLIT ? 16384 : 8192);
    u16* lB_l = buf + 24576;

    bf16x8 bhf[4], blf[4];
#pragma unroll
    for (int j = 0; j < 4; ++j) {
      bhf[j] = ldsfrag(lB_h, wn + j * 16 + l16, quad);
      if (SPLIT) blf[j] = ldsfrag(lB_l, wn + j * 16 + l16, quad);
    }
#pragma unroll
    for (int i = 0; i < 8; ++i) {
      bf16x8 ah = ldsfrag(lA_h, wm + i * 16 + l16, quad);
      bf16x8 al;
      if (SPLIT) al = ldsfrag(lA_l, wm + i * 16 + l16, quad);
#pragma unroll
      for (int j = 0; j < 4; ++j) {
        acc[i][j] = mfma16(ah, bhf[j], acc[i][j]);
        if (SPLIT) {
          acc[i][j] = mfma16(ah, blf[j], acc[i][j]);
          acc[i][j] = mfma16(al, bhf[j], acc[i][j]);
        }
      }
    }
    // DBUF: drains the prefetch (which had the whole MFMA block to land) and
    // releases buf[cur]. Single-buffer: all waves done reading before the
    // next stage overwrites.
    __syncthreads();
    cur ^= 1;
  }

  // epilogue: C/D layout col = lane&15, row = quad*4 + reg
#pragma unroll
  for (int i = 0; i < 8; ++i) {
#pragma unroll
    for (int j = 0; j < 4; ++j) {
      int col = n0 + wn + j * 16 + l16;
#pragma unroll
      for (int r = 0; r < 4; ++r) {
        int row = m0 + wm + i * 16 + quad * 4 + r;
        size_t idx = cOff + (size_t)row * ldc + col;
        float v = acc[i][j][r];
        if (OMODE == 0) {
          ((float*)C0)[idx] = v;
        } else if (OMODE == 1) {
          ((u16*)C0)[idx] = f2bf(v);
        } else {
          u16 h = f2bf(v);
          ((u16*)C0)[idx] = h;
          ((u16*)C1)[idx] = f2bf(v - bf2f(h));
        }
      }
    }
  }
}

// ---------------- softmax over rows of 512 fp32 -> bf16 --------------------
__global__ __launch_bounds__(256) void softmax_rows(
    const float* __restrict__ in, u16* __restrict__ out) {
  int row = blockIdx.x * 4 + (threadIdx.x >> 6);
  int lane = threadIdx.x & 63;
  const float* p = in + (size_t)row * 512 + lane * 8;
  float4 v0 = *(const float4*)p;
  float4 v1 = *(const float4*)(p + 4);
  float v[8] = {v0.x, v0.y, v0.z, v0.w, v1.x, v1.y, v1.z, v1.w};
  float m = v[0];
#pragma unroll
  for (int i = 1; i < 8; ++i) m = fmaxf(m, v[i]);
#pragma unroll
  for (int o = 32; o > 0; o >>= 1) m = fmaxf(m, __shfl_xor(m, o));
  float s = 0.f;
#pragma unroll
  for (int i = 0; i < 8; ++i) {
    v[i] = __expf(v[i] - m);
    s += v[i];
  }
#pragma unroll
  for (int o = 32; o > 0; o >>= 1) s += __shfl_xor(s, o);
  float inv = 1.0f / s;
  u16x8s rr;
#pragma unroll
  for (int i = 0; i < 8; ++i) rr[i] = f2bf(v[i] * inv);
  *(u16x8s*)(out + (size_t)row * 512 + lane * 8) = rr;
}

// ---------------------------------------------------------------------------
extern "C" void kernel_launch(void* const* d_in, const int* in_sizes, int n_in,
                              void* d_out, int out_size, void* d_ws,
                              size_t ws_size, hipStream_t stream) {
  const float* x = (const float*)d_in[0];   // [16,512,512]  = [8192,512]
  const float* wq = (const float*)d_in[1];  // [512,4096]
  const float* wk = (const float*)d_in[2];
  const float* wv = (const float*)d_in[3];
  float* out = (float*)d_out;               // [16,512,4096]
  char* ws = (char*)d_ws;

  const size_t MB = 1024ull * 1024ull;
  u16* XHI = (u16*)(ws + 0 * MB);    // [8192,512] bf16 hi      8MB
  u16* XLO = (u16*)(ws + 8 * MB);    //                         8MB
  u16* WQH = (u16*)(ws + 16 * MB);   // wq split, orig layout   4MB
  u16* WQL = (u16*)(ws + 20 * MB);
  u16* WKH = (u16*)(ws + 24 * MB);
  u16* WKL = (u16*)(ws + 28 * MB);
  u16* WVTH = (u16*)(ws + 32 * MB);  // wv^T [4096,512]         4MB
  u16* WVTL = (u16*)(ws + 36 * MB);
  u16* MPH = (u16*)(ws + 40 * MB);   // M' = Wk Wq^T [8,512,512] 4MB
  u16* MPL = (u16*)(ws + 44 * MB);
  u16* THI = (u16*)(ws + 48 * MB);   // T = X M'^T [8,8192,512] 64MB
  u16* TLO = (u16*)(ws + 112 * MB);  //                         64MB
  u16* VT = (u16*)(ws + 176 * MB);   // V^T [4096,8192] bf16    64MB
  float* LOG = (float*)(ws + 240 * MB);  // logits [128,512,512] 128MB
  u16* P = THI;                      // probs alias T (T dead after logits)
  // total ws used: 368MB

  // --- prep ---
  split_hl_kernel<<<4096, 256, 0, stream>>>(x, XHI, XLO, 1048576);
  split_hl_kernel<<<2048, 256, 0, stream>>>(wq, WQH, WQL, 524288);
  split_hl_kernel<<<2048, 256, 0, stream>>>(wk, WKH, WKL, 524288);
  transpose_split_w<<<dim3(128, 16), dim3(32, 8), 0, stream>>>(wv, WVTH, WVTL);

  // --- M'_h = Wk_h Wq_h^T : [512,512] per head, x3 split, hi/lo out ---
  // (stays on the 128^2 kernel: at 256^2 it would be only 32 blocks)
  gemm_bt<1, 2><<<dim3(4, 4, 8), 256, 0, stream>>>(
      WKH, WKL, WQH, WQL, MPH, MPL, 4096, 4096, 512, 512,
      /*aH*/ 0, /*aB*/ 512, /*bH*/ 0, /*bB*/ 512, /*cH*/ 0, /*cB*/ 262144);

  // --- T_h = X M'_h^T : [8192,512] per head, x3, hi/lo out ---
  // single-buffer variant: 64KiB LDS -> 2 blocks/CU, all 512 co-resident
  gemm256<1, 2, 0><<<dim3(2, 32, 8), 512, 0, stream>>>(
      XHI, XLO, MPH, MPL, THI, TLO, 512, 512, 512, 512,
      0, 0, 0, 262144, 0, 4194304);

  // --- V^T = Wv^T X^T : [4096 d, 8192 s], plain bf16 (dbuf, 64KiB) ---
  gemm256<0, 1, 1><<<dim3(32, 16, 1), 512, 0, stream>>>(
      WVTH, WVTH, XHI, XHI, VT, nullptr, 512, 512, 8192, 512,
      0, 0, 0, 0, 0, 0);

  // --- logits_hb = T_h[b] X[b]^T : [512,512] per (h,b), x3, fp32 out ---
  gemm256<1, 0, 0><<<dim3(2, 2, 128), 512, 0, stream>>>(
      THI, TLO, XHI, XLO, LOG, nullptr, 512, 512, 512, 512,
      /*aH*/ 4194304, /*aB*/ 262144, /*bH*/ 0, /*bB*/ 262144,
      /*cH*/ 4194304, /*cB*/ 262144);

  // --- P = softmax(logits) rows, bf16 (aliases THI) ---
  softmax_rows<<<16384, 256, 0, stream>>>(LOG, P);

  // --- out_hb = P_hb V_hb : [512 q, 512 d], plain bf16 -> fp32 out,
  //     written interleaved: out[(b*512+q)*4096 + h*512 + d] ---
  gemm256<0, 0, 1><<<dim3(2, 2, 128), 512, 0, stream>>>(
      P, P, VT, VT, out, nullptr, 512, 8192, 4096, 512,
      /*aH*/ 4194304, /*aB*/ 262144, /*bH*/ 4194304, /*bB*/ 512,
      /*cH*/ 512, /*cB*/ 2097152);
}

// Round 7
// 522.237 us; speedup vs baseline: 4.1455x; 4.1455x over previous
//
#include <hip/hip_runtime.h>

// ---------------------------------------------------------------------------
// MultiHead_BlockAttention: out[b,s,h*512+d] = softmax(Q Kt) V  per (h,b)
//   Q = x@wq, K = x@wk, V = x@wv ; head h = cols [h*512,(h+1)*512)
// Trick: logits = X (Wq Wk^T) X^T  -> precompute M' = Wk Wq^T per head.
// Precision: bf16 hi/lo split (3 MFMAs) on the logit path; plain bf16 for V/P.
// R1: T/logits -> gemm256 (256x256, 8 waves, dbuf, 2-phase). 551us.
// R3: PV and VT moved to gemm256 too. 513us.
// R4: intra-step barriers REGRESSED. R5: SGB NULL. R6: launch_bounds(512,4)
//     -> VGPR cap 64 -> acc spilled to scratch (2GB writes) -> 2165us. The
//     256^2 tile is register-bound to 1 block/CU; never force occupancy.
// R7: depth-2 pipeline via half-buffer regions + counted vmcnt (T3+T4):
//     regions A[2], B[2]. Step t: ph0{issue A(t+1)->A[q]; read B-frags +
//     i0..3; lgkm0; barrier}  ph1{issue B(t+2)->B[p] (B[p] freed by ph0
//     barrier); i4..7; lgkm0; vmcnt(4) counted; barrier}. B staged 1.5 steps
//     ahead, A 1 step; end-of-step wait leaves newest B-group in flight.
// ---------------------------------------------------------------------------

typedef unsigned short u16;
typedef __bf16 bf16x8 __attribute__((ext_vector_type(8)));
typedef unsigned short u16x4 __attribute__((ext_vector_type(4)));
typedef unsigned short u16x8s __attribute__((ext_vector_type(8)));
typedef float f32x4 __attribute__((ext_vector_type(4)));

typedef __attribute__((address_space(1))) void gvoid_t;
typedef __attribute__((address_space(3))) void svoid_t;

__device__ __forceinline__ u16 f2bf(float f) {
  unsigned u = __float_as_uint(f);
  u = (u + 0x7fffu + ((u >> 16) & 1u)) >> 16;  // RTN-even
  return (u16)u;
}
__device__ __forceinline__ float bf2f(u16 h) {
  return __uint_as_float(((unsigned)h) << 16);
}

__device__ __forceinline__ f32x4 mfma16(bf16x8 a, bf16x8 b, f32x4 c) {
  return __builtin_amdgcn_mfma_f32_16x16x32_bf16(a, b, c, 0, 0, 0);
}

// ---------------- prep: fp32 -> bf16 hi/lo split (same layout) -------------
__global__ __launch_bounds__(256) void split_hl_kernel(
    const float* __restrict__ in, u16* __restrict__ hi, u16* __restrict__ lo,
    int n4) {
  int i = blockIdx.x * 256 + threadIdx.x;
  if (i >= n4) return;
  float4 v = ((const float4*)in)[i];
  float vv[4] = {v.x, v.y, v.z, v.w};
  u16x4 h, l;
#pragma unroll
  for (int j = 0; j < 4; ++j) {
    u16 hh = f2bf(vv[j]);
    h[j] = hh;
    l[j] = f2bf(vv[j] - bf2f(hh));
  }
  ((u16x4*)hi)[i] = h;
  ((u16x4*)lo)[i] = l;
}

// ---------------- prep: transpose [512,4096] -> [4096,512] + split ---------
__global__ __launch_bounds__(256) void transpose_split_w(
    const float* __restrict__ in, u16* __restrict__ hi, u16* __restrict__ lo) {
  __shared__ float t[32][33];
  int d0 = blockIdx.x * 32, f0 = blockIdx.y * 32;
  int tx = threadIdx.x, ty = threadIdx.y;  // blockDim = (32,8)
#pragma unroll
  for (int r = 0; r < 4; ++r)
    t[ty + r * 8][tx] = in[(size_t)(f0 + ty + r * 8) * 4096 + d0 + tx];
  __syncthreads();
#pragma unroll
  for (int r = 0; r < 4; ++r) {
    float v = t[tx][ty + r * 8];  // = in[f0+tx][d0+ty+r*8]
    int d = d0 + ty + r * 8, f = f0 + tx;
    u16 h = f2bf(v);
    size_t idx = (size_t)d * 512 + f;
    hi[idx] = h;
    lo[idx] = f2bf(v - bf2f(h));
  }
}

// ---------------- shared LDS swizzle helpers -------------------------------
// LDS tiles [rows][32 k] bf16, XOR-swizzled at 16B-chunk granularity:
//   chunk (m,cq) stored at chunk col c' = cq ^ ((m>>1)&3)  (involution)
// so frag ds_read_b128 is <=2-way bank conflicted (free) AND staging stays
// compatible with global_load_lds's "base + lane*16" placement rule.
__device__ __forceinline__ bf16x8 ldsfrag(const u16* tile, int row, int quad) {
  int c = quad ^ ((row >> 1) & 3);
  return *(const bf16x8*)(tile + row * 32 + c * 8);
}

// ---------------- GEMM core (legacy 128x128): C[m][n] = sum_k A[m][k]B[n][k]
// 128x128 tile, BK=32, 256 threads (4 waves, each 64x64 = 4x4 frags of 16x16).
__device__ __forceinline__ void stage_tile(u16* ldsTile, const u16* g0, int ld,
                                           int wave, int lane) {
#pragma unroll
  for (int r = 0; r < 2; ++r) {
    int p = r * 256 + wave * 64 + lane;          // LDS chunk position
    int m = p >> 2;
    int cq = (p & 3) ^ ((m >> 1) & 3);           // global chunk col
    const u16* g = g0 + (size_t)m * ld + cq * 8;
    u16* l = ldsTile + (size_t)(r * 256 + wave * 64) * 8;  // wave-uniform
    __builtin_amdgcn_global_load_lds((gvoid_t*)g, (svoid_t*)l, 16, 0, 0);
  }
}

// OMODE: 0 = fp32 to C0 ; 1 = bf16 to C0 ; 2 = hi/lo bf16 to C0/C1
template <int SPLIT, int OMODE>
__global__ __launch_bounds__(256, 2) void gemm_bt(
    const u16* __restrict__ Ah, const u16* __restrict__ Al,
    const u16* __restrict__ Bh, const u16* __restrict__ Bl,
    void* __restrict__ C0, void* __restrict__ C1, int lda, int ldb, int ldc,
    int K, size_t aH, size_t aB, size_t bH, size_t bB, size_t cH, size_t cB) {
  __shared__ __align__(16) u16 lds[(SPLIT ? 4 : 2) * 4096];
  u16* lAh = lds;
  u16* lAl = SPLIT ? (lds + 4096) : lds;
  u16* lBh = lds + (SPLIT ? 8192 : 4096);
  u16* lBl = SPLIT ? (lds + 12288) : lds;

  const int zh = blockIdx.z >> 4, zb = blockIdx.z & 15;
  Ah += zh * aH + zb * aB;
  Al += zh * aH + zb * aB;
  Bh += zh * bH + zb * bB;
  Bl += zh * bH + zb * bB;
  const size_t cOff = zh * cH + zb * cB;

  const int m0 = blockIdx.y * 128, n0 = blockIdx.x * 128;
  const int tid = threadIdx.x;
  const int wave = tid >> 6, lane = tid & 63;
  const int quad = lane >> 4, l16 = lane & 15;
  const int wm = (wave >> 1) * 64, wn = (wave & 1) * 64;

  f32x4 acc[4][4] = {};

  for (int k0 = 0; k0 < K; k0 += 32) {
    stage_tile(lAh, Ah + (size_t)m0 * lda + k0, lda, wave, lane);
    if (SPLIT) stage_tile(lAl, Al + (size_t)m0 * lda + k0, lda, wave, lane);
    stage_tile(lBh, Bh + (size_t)n0 * ldb + k0, ldb, wave, lane);
    if (SPLIT) stage_tile(lBl, Bl + (size_t)n0 * ldb + k0, ldb, wave, lane);
    __syncthreads();

    bf16x8 a_h[4], a_l[4], b_h[4], b_l[4];
#pragma unroll
    for (int i = 0; i < 4; ++i) {
      a_h[i] = ldsfrag(lAh, wm + i * 16 + l16, quad);
      b_h[i] = ldsfrag(lBh, wn + i * 16 + l16, quad);
      if (SPLIT) {
        a_l[i] = ldsfrag(lAl, wm + i * 16 + l16, quad);
        b_l[i] = ldsfrag(lBl, wn + i * 16 + l16, quad);
      }
    }
#pragma unroll
    for (int i = 0; i < 4; ++i)
#pragma unroll
      for (int j = 0; j < 4; ++j) {
        acc[i][j] = mfma16(a_h[i], b_h[j], acc[i][j]);
        if (SPLIT) {
          acc[i][j] = mfma16(a_h[i], b_l[j], acc[i][j]);
          acc[i][j] = mfma16(a_l[i], b_h[j], acc[i][j]);
        }
      }
    __syncthreads();
  }

  // epilogue: C/D layout col = lane&15, row = quad*4 + reg (m89/m91 verified)
#pragma unroll
  for (int i = 0; i < 4; ++i) {
#pragma unroll
    for (int j = 0; j < 4; ++j) {
      int col = n0 + wn + j * 16 + l16;
#pragma unroll
      for (int r = 0; r < 4; ++r) {
        int row = m0 + wm + i * 16 + quad * 4 + r;
        size_t idx = cOff + (size_t)row * ldc + col;
        float v = acc[i][j][r];
        if (OMODE == 0) {
          ((float*)C0)[idx] = v;
        } else if (OMODE == 1) {
          ((u16*)C0)[idx] = f2bf(v);
        } else {
          u16 h = f2bf(v);
          ((u16*)C0)[idx] = h;
          ((u16*)C1)[idx] = f2bf(v - bf2f(h));
        }
      }
    }
  }
}

// ---------------- GEMM core (256x256, 8 waves, depth-2 pipeline) -----------
// 256x256 tile, BK=32, 512 threads. Wave w = (w>>2, w&3) owns a 128x64
// sub-tile = acc[8][4] of 16x16 frags. LDS regions A[2] + B[2]:
//   split: 4 x 32 KiB = 128 KiB; non-split: 4 x 16 KiB = 64 KiB.
// Region lifetime proof: B[p] reads all happen in ph0 (B-frags held in
// registers for ph1), certified complete by lgkmcnt(0)+barrier#1 -> restage
// B(t+2) into B[p] legal in ph1. A[q] (= region read in step t-1) is free
// after barrier#2 of t-1 -> restage A(t+1) in t.ph0. DMA completion guards:
// end-of-step counted vmcnt leaves ONLY the newest B-group in flight, so
// A(t+1) [issued 1 step ahead] and B(t+1) [1.5 steps ahead] are landed.
__device__ __forceinline__ void stage256(u16* tile, const u16* g0, int ld,
                                         int tid) {
  const int wave = tid >> 6;
#pragma unroll
  for (int r = 0; r < 2; ++r) {
    int p = r * 512 + tid;                        // chunk index 0..1023
    int m = p >> 2;                               // row 0..255
    int cq = (p & 3) ^ ((m >> 1) & 3);            // global chunk col
    const u16* g = g0 + (size_t)m * ld + cq * 8;
    u16* l = tile + (size_t)(r * 512 + wave * 64) * 8;  // wave-uniform base
    __builtin_amdgcn_global_load_lds((gvoid_t*)g, (svoid_t*)l, 16, 0, 0);
  }
}

template <int SPLIT, int OMODE>
__global__ __launch_bounds__(512, 2) void gemm256(
    const u16* __restrict__ Ah, const u16* __restrict__ Al,
    const u16* __restrict__ Bh, const u16* __restrict__ Bl,
    void* __restrict__ C0, void* __restrict__ C1, int lda, int ldb, int ldc,
    int K, size_t aH, size_t aB, size_t bH, size_t bB, size_t cH, size_t cB) {
  constexpr int REG = (SPLIT ? 2 : 1) * 8192;  // u16 per region per buffer
  __shared__ __align__(16) u16 lds[4 * REG];   // A0 A1 B0 B1

  // ---- bijective XCD swizzle: XCD k gets contiguous work chunk k ----
  const int gx = gridDim.x, gy = gridDim.y;
  const int nb = gx * gy * (int)gridDim.z;
  int orig = blockIdx.x + gx * (blockIdx.y + gy * blockIdx.z);
  int swz = orig;
  if ((nb & 7) == 0) swz = (orig & 7) * (nb >> 3) + (orig >> 3);
  const int bx = swz % gx;
  const int byz = swz / gx;
  const int by = byz % gy;
  const int bz = byz / gy;

  const int zh = bz >> 4, zb = bz & 15;
  Ah += zh * aH + zb * aB;
  Al += zh * aH + zb * aB;
  Bh += zh * bH + zb * bB;
  Bl += zh * bH + zb * bB;
  const size_t cOff = zh * cH + zb * cB;

  const int m0 = by * 256, n0 = bx * 256;
  const int tid = threadIdx.x;
  const int wave = tid >> 6, lane = tid & 63;
  const int quad = lane >> 4, l16 = lane & 15;
  const int wm = (wave >> 2) * 128, wn = (wave & 3) * 64;

  const u16* gA_h = Ah + (size_t)m0 * lda;
  const u16* gA_l = Al + (size_t)m0 * lda;
  const u16* gB_h = Bh + (size_t)n0 * ldb;
  const u16* gB_l = Bl + (size_t)n0 * ldb;

#define STAGE_A(dst, kk)                                  \
  do {                                                    \
    stage256((dst), gA_h + (kk), lda, tid);               \
    if (SPLIT) stage256((dst) + 8192, gA_l + (kk), lda, tid); \
  } while (0)
#define STAGE_B(dst, kk)                                  \
  do {                                                    \
    stage256((dst), gB_h + (kk), ldb, tid);               \
    if (SPLIT) stage256((dst) + 8192, gB_l + (kk), ldb, tid); \
  } while (0)
#define WAIT_VM_PART()                                             \
  do {                                                             \
    if (SPLIT)                                                     \
      asm volatile("s_waitcnt vmcnt(4)" ::: "memory");             \
    else                                                           \
      asm volatile("s_waitcnt vmcnt(2)" ::: "memory");             \
  } while (0)

  f32x4 acc[8][4] = {};

  const int NT = K >> 5;  // K / 32

  // ---- prologue: B(0), A(0), B(1); wait leaves B(1) in flight ----
  STAGE_B(lds + 2 * REG, 0);
  STAGE_A(lds, 0);
  if (NT > 1) {
    STAGE_B(lds + 3 * REG, 32);
    WAIT_VM_PART();
  } else {
    asm volatile("s_waitcnt vmcnt(0)" ::: "memory");
  }
  __builtin_amdgcn_s_barrier();

  for (int t = 0; t < NT; ++t) {
    const int p = t & 1, q = p ^ 1;
    const int k0 = t << 5;
    u16* Ap = lds + p * REG;
    u16* Aq = lds + q * REG;
    u16* Bp = lds + (2 + p) * REG;
    u16* lA_h = Ap, *lA_l = Ap + 8192;
    u16* lB_h = Bp, *lB_l = Bp + 8192;

    // ---- ph0: issue A(t+1); B-frags + i0..3 from current regions ----
    if (t + 1 < NT) STAGE_A(Aq, k0 + 32);

    bf16x8 bhf[4], blf[4];
#pragma unroll
    for (int j = 0; j < 4; ++j) {
      bhf[j] = ldsfrag(lB_h, wn + j * 16 + l16, quad);
      if (SPLIT) blf[j] = ldsfrag(lB_l, wn + j * 16 + l16, quad);
    }
#pragma unroll
    for (int i = 0; i < 4; ++i) {
      bf16x8 ah = ldsfrag(lA_h, wm + i * 16 + l16, quad);
      bf16x8 al;
      if (SPLIT) al = ldsfrag(lA_l, wm + i * 16 + l16, quad);
#pragma unroll
      for (int j = 0; j < 4; ++j) {
        acc[i][j] = mfma16(ah, bhf[j], acc[i][j]);
        if (SPLIT) {
          acc[i][j] = mfma16(ah, blf[j], acc[i][j]);
          acc[i][j] = mfma16(al, bhf[j], acc[i][j]);
        }
      }
    }
    asm volatile("s_waitcnt lgkmcnt(0)" ::: "memory");
    __builtin_amdgcn_sched_barrier(0);
    __builtin_amdgcn_s_barrier();   // barrier#1: B[p] fully consumed

    // ---- ph1: issue B(t+2) into freed B[p]; i4..7 ----
    if (t + 2 < NT) STAGE_B(Bp, k0 + 64);
#pragma unroll
    for (int i = 4; i < 8; ++i) {
      bf16x8 ah = ldsfrag(lA_h, wm + i * 16 + l16, quad);
      bf16x8 al;
      if (SPLIT) al = ldsfrag(lA_l, wm + i * 16 + l16, quad);
#pragma unroll
      for (int j = 0; j < 4; ++j) {
        acc[i][j] = mfma16(ah, bhf[j], acc[i][j]);
        if (SPLIT) {
          acc[i][j] = mfma16(ah, blf[j], acc[i][j]);
          acc[i][j] = mfma16(al, bhf[j], acc[i][j]);
        }
      }
    }
    asm volatile("s_waitcnt lgkmcnt(0)" ::: "memory");
    __builtin_amdgcn_sched_barrier(0);
    // counted wait: A(t+1), B(t+1) must be landed; newest B(t+2) may fly
    if (t + 2 < NT) {
      WAIT_VM_PART();
    } else {
      asm volatile("s_waitcnt vmcnt(0)" ::: "memory");
    }
    __builtin_amdgcn_s_barrier();   // barrier#2: step boundary
  }
#undef STAGE_A
#undef STAGE_B
#undef WAIT_VM_PART

  // epilogue: C/D layout col = lane&15, row = quad*4 + reg
#pragma unroll
  for (int i = 0; i < 8; ++i) {
#pragma unroll
    for (int j = 0; j < 4; ++j) {
      int col = n0 + wn + j * 16 + l16;
#pragma unroll
      for (int r = 0; r < 4; ++r) {
        int row = m0 + wm + i * 16 + quad * 4 + r;
        size_t idx = cOff + (size_t)row * ldc + col;
        float v = acc[i][j][r];
        if (OMODE == 0) {
          ((float*)C0)[idx] = v;
        } else if (OMODE == 1) {
          ((u16*)C0)[idx] = f2bf(v);
        } else {
          u16 h = f2bf(v);
          ((u16*)C0)[idx] = h;
          ((u16*)C1)[idx] = f2bf(v - bf2f(h));
        }
      }
    }
  }
}

// ---------------- softmax over rows of 512 fp32 -> bf16 --------------------
__global__ __launch_bounds__(256) void softmax_rows(
    const float* __restrict__ in, u16* __restrict__ out) {
  int row = blockIdx.x * 4 + (threadIdx.x >> 6);
  int lane = threadIdx.x & 63;
  const float* p = in + (size_t)row * 512 + lane * 8;
  float4 v0 = *(const float4*)p;
  float4 v1 = *(const float4*)(p + 4);
  float v[8] = {v0.x, v0.y, v0.z, v0.w, v1.x, v1.y, v1.z, v1.w};
  float m = v[0];
#pragma unroll
  for (int i = 1; i < 8; ++i) m = fmaxf(m, v[i]);
#pragma unroll
  for (int o = 32; o > 0; o >>= 1) m = fmaxf(m, __shfl_xor(m, o));
  float s = 0.f;
#pragma unroll
  for (int i = 0; i < 8; ++i) {
    v[i] = __expf(v[i] - m);
    s += v[i];
  }
#pragma unroll
  for (int o = 32; o > 0; o >>= 1) s += __shfl_xor(s, o);
  float inv = 1.0f / s;
  u16x8s rr;
#pragma unroll
  for (int i = 0; i < 8; ++i) rr[i] = f2bf(v[i] * inv);
  *(u16x8s*)(out + (size_t)row * 512 + lane * 8) = rr;
}

// ---------------------------------------------------------------------------
extern "C" void kernel_launch(void* const* d_in, const int* in_sizes, int n_in,
                              void* d_out, int out_size, void* d_ws,
                              size_t ws_size, hipStream_t stream) {
  const float* x = (const float*)d_in[0];   // [16,512,512]  = [8192,512]
  const float* wq = (const float*)d_in[1];  // [512,4096]
  const float* wk = (const float*)d_in[2];
  const float* wv = (const float*)d_in[3];
  float* out = (float*)d_out;               // [16,512,4096]
  char* ws = (char*)d_ws;

  const size_t MB = 1024ull * 1024ull;
  u16* XHI = (u16*)(ws + 0 * MB);    // [8192,512] bf16 hi      8MB
  u16* XLO = (u16*)(ws + 8 * MB);    //                         8MB
  u16* WQH = (u16*)(ws + 16 * MB);   // wq split, orig layout   4MB
  u16* WQL = (u16*)(ws + 20 * MB);
  u16* WKH = (u16*)(ws + 24 * MB);
  u16* WKL = (u16*)(ws + 28 * MB);
  u16* WVTH = (u16*)(ws + 32 * MB);  // wv^T [4096,512]         4MB
  u16* WVTL = (u16*)(ws + 36 * MB);
  u16* MPH = (u16*)(ws + 40 * MB);   // M' = Wk Wq^T [8,512,512] 4MB
  u16* MPL = (u16*)(ws + 44 * MB);
  u16* THI = (u16*)(ws + 48 * MB);   // T = X M'^T [8,8192,512] 64MB
  u16* TLO = (u16*)(ws + 112 * MB);  //                         64MB
  u16* VT = (u16*)(ws + 176 * MB);   // V^T [4096,8192] bf16    64MB
  float* LOG = (float*)(ws + 240 * MB);  // logits [128,512,512] 128MB
  u16* P = THI;                      // probs alias T (T dead after logits)
  // total ws used: 368MB

  // --- prep ---
  split_hl_kernel<<<4096, 256, 0, stream>>>(x, XHI, XLO, 1048576);
  split_hl_kernel<<<2048, 256, 0, stream>>>(wq, WQH, WQL, 524288);
  split_hl_kernel<<<2048, 256, 0, stream>>>(wk, WKH, WKL, 524288);
  transpose_split_w<<<dim3(128, 16), dim3(32, 8), 0, stream>>>(wv, WVTH, WVTL);

  // --- M'_h = Wk_h Wq_h^T : [512,512] per head, x3 split, hi/lo out ---
  // (stays on the 128^2 kernel: at 256^2 it would be only 32 blocks)
  gemm_bt<1, 2><<<dim3(4, 4, 8), 256, 0, stream>>>(
      WKH, WKL, WQH, WQL, MPH, MPL, 4096, 4096, 512, 512,
      /*aH*/ 0, /*aB*/ 512, /*bH*/ 0, /*bB*/ 512, /*cH*/ 0, /*cB*/ 262144);

  // --- T_h = X M'_h^T : [8192,512] per head, x3, hi/lo out ---
  gemm256<1, 2><<<dim3(2, 32, 8), 512, 0, stream>>>(
      XHI, XLO, MPH, MPL, THI, TLO, 512, 512, 512, 512,
      0, 0, 0, 262144, 0, 4194304);

  // --- V^T = Wv^T X^T : [4096 d, 8192 s], plain bf16 ---
  gemm256<0, 1><<<dim3(32, 16, 1), 512, 0, stream>>>(
      WVTH, WVTH, XHI, XHI, VT, nullptr, 512, 512, 8192, 512,
      0, 0, 0, 0, 0, 0);

  // --- logits_hb = T_h[b] X[b]^T : [512,512] per (h,b), x3, fp32 out ---
  gemm256<1, 0><<<dim3(2, 2, 128), 512, 0, stream>>>(
      THI, TLO, XHI, XLO, LOG, nullptr, 512, 512, 512, 512,
      /*aH*/ 4194304, /*aB*/ 262144, /*bH*/ 0, /*bB*/ 262144,
      /*cH*/ 4194304, /*cB*/ 262144);

  // --- P = softmax(logits) rows, bf16 (aliases THI) ---
  softmax_rows<<<16384, 256, 0, stream>>>(LOG, P);

  // --- out_hb = P_hb V_hb : [512 q, 512 d], plain bf16 -> fp32 out,
  //     written interleaved: out[(b*512+q)*4096 + h*512 + d] ---
  gemm256<0, 0><<<dim3(2, 2, 128), 512, 0, stream>>>(
      P, P, VT, VT, out, nullptr, 512, 8192, 4096, 512,
      /*aH*/ 4194304, /*aB*/ 262144, /*bH*/ 4194304, /*bB*/ 512,
      /*cH*/ 512, /*cB*/ 2097152);
}

// Round 8
// 499.084 us; speedup vs baseline: 4.3378x; 1.0464x over previous
//
#include <hip/hip_runtime.h>

// ---------------------------------------------------------------------------
// MultiHead_BlockAttention: out[b,s,h*512+d] = softmax(Q Kt) V  per (h,b)
//   Q = x@wq, K = x@wk, V = x@wv ; head h = cols [h*512,(h+1)*512)
// Trick: logits = X (Wq Wk^T) X^T  -> precompute M' = Wk Wq^T per head.
// Precision: bf16 hi/lo split (3 MFMAs) on the logit path; plain bf16 for V/P.
// R1: T/logits -> gemm256 (256x256, 8 waves, dbuf, 2-phase). 551us.
// R3: PV and VT moved to gemm256 too. 513us.
// R4 barriers / R5 SGB / R7 depth-2 vmcnt: all null or regressed -> the
//     split-GEMM K-step schedule is at its structural ceiling (~110us).
// R8: FUSE softmax into the logits GEMM. Tile 128x512 (full softmax row per
//     block), epilogue does row-softmax (shfl strip reduce + 4KB LDS cross-
//     wave reduce) and writes P bf16 directly. Eliminates the 134MB fp32 LOG
//     write + 132MB read + the softmax dispatch. gemm256 reverted to R3.
// ---------------------------------------------------------------------------

typedef unsigned short u16;
typedef __bf16 bf16x8 __attribute__((ext_vector_type(8)));
typedef unsigned short u16x4 __attribute__((ext_vector_type(4)));
typedef unsigned short u16x8s __attribute__((ext_vector_type(8)));
typedef float f32x4 __attribute__((ext_vector_type(4)));

typedef __attribute__((address_space(1))) void gvoid_t;
typedef __attribute__((address_space(3))) void svoid_t;

__device__ __forceinline__ u16 f2bf(float f) {
  unsigned u = __float_as_uint(f);
  u = (u + 0x7fffu + ((u >> 16) & 1u)) >> 16;  // RTN-even
  return (u16)u;
}
__device__ __forceinline__ float bf2f(u16 h) {
  return __uint_as_float(((unsigned)h) << 16);
}

__device__ __forceinline__ f32x4 mfma16(bf16x8 a, bf16x8 b, f32x4 c) {
  return __builtin_amdgcn_mfma_f32_16x16x32_bf16(a, b, c, 0, 0, 0);
}

// ---------------- prep: fp32 -> bf16 hi/lo split (same layout) -------------
__global__ __launch_bounds__(256) void split_hl_kernel(
    const float* __restrict__ in, u16* __restrict__ hi, u16* __restrict__ lo,
    int n4) {
  int i = blockIdx.x * 256 + threadIdx.x;
  if (i >= n4) return;
  float4 v = ((const float4*)in)[i];
  float vv[4] = {v.x, v.y, v.z, v.w};
  u16x4 h, l;
#pragma unroll
  for (int j = 0; j < 4; ++j) {
    u16 hh = f2bf(vv[j]);
    h[j] = hh;
    l[j] = f2bf(vv[j] - bf2f(hh));
  }
  ((u16x4*)hi)[i] = h;
  ((u16x4*)lo)[i] = l;
}

// ---------------- prep: transpose [512,4096] -> [4096,512] + split ---------
__global__ __launch_bounds__(256) void transpose_split_w(
    const float* __restrict__ in, u16* __restrict__ hi, u16* __restrict__ lo) {
  __shared__ float t[32][33];
  int d0 = blockIdx.x * 32, f0 = blockIdx.y * 32;
  int tx = threadIdx.x, ty = threadIdx.y;  // blockDim = (32,8)
#pragma unroll
  for (int r = 0; r < 4; ++r)
    t[ty + r * 8][tx] = in[(size_t)(f0 + ty + r * 8) * 4096 + d0 + tx];
  __syncthreads();
#pragma unroll
  for (int r = 0; r < 4; ++r) {
    float v = t[tx][ty + r * 8];  // = in[f0+tx][d0+ty+r*8]
    int d = d0 + ty + r * 8, f = f0 + tx;
    u16 h = f2bf(v);
    size_t idx = (size_t)d * 512 + f;
    hi[idx] = h;
    lo[idx] = f2bf(v - bf2f(h));
  }
}

// ---------------- shared LDS swizzle helpers -------------------------------
// LDS tiles [rows][32 k] bf16, XOR-swizzled at 16B-chunk granularity:
//   chunk (m,cq) stored at chunk col c' = cq ^ ((m>>1)&3)  (involution)
__device__ __forceinline__ bf16x8 ldsfrag(const u16* tile, int row, int quad) {
  int c = quad ^ ((row >> 1) & 3);
  return *(const bf16x8*)(tile + row * 32 + c * 8);
}

// ---------------- GEMM core (legacy 128x128) -------------------------------
__device__ __forceinline__ void stage_tile(u16* ldsTile, const u16* g0, int ld,
                                           int wave, int lane) {
#pragma unroll
  for (int r = 0; r < 2; ++r) {
    int p = r * 256 + wave * 64 + lane;          // LDS chunk position
    int m = p >> 2;
    int cq = (p & 3) ^ ((m >> 1) & 3);           // global chunk col
    const u16* g = g0 + (size_t)m * ld + cq * 8;
    u16* l = ldsTile + (size_t)(r * 256 + wave * 64) * 8;  // wave-uniform
    __builtin_amdgcn_global_load_lds((gvoid_t*)g, (svoid_t*)l, 16, 0, 0);
  }
}

// OMODE: 0 = fp32 to C0 ; 1 = bf16 to C0 ; 2 = hi/lo bf16 to C0/C1
template <int SPLIT, int OMODE>
__global__ __launch_bounds__(256, 2) void gemm_bt(
    const u16* __restrict__ Ah, const u16* __restrict__ Al,
    const u16* __restrict__ Bh, const u16* __restrict__ Bl,
    void* __restrict__ C0, void* __restrict__ C1, int lda, int ldb, int ldc,
    int K, size_t aH, size_t aB, size_t bH, size_t bB, size_t cH, size_t cB) {
  __shared__ __align__(16) u16 lds[(SPLIT ? 4 : 2) * 4096];
  u16* lAh = lds;
  u16* lAl = SPLIT ? (lds + 4096) : lds;
  u16* lBh = lds + (SPLIT ? 8192 : 4096);
  u16* lBl = SPLIT ? (lds + 12288) : lds;

  const int zh = blockIdx.z >> 4, zb = blockIdx.z & 15;
  Ah += zh * aH + zb * aB;
  Al += zh * aH + zb * aB;
  Bh += zh * bH + zb * bB;
  Bl += zh * bH + zb * bB;
  const size_t cOff = zh * cH + zb * cB;

  const int m0 = blockIdx.y * 128, n0 = blockIdx.x * 128;
  const int tid = threadIdx.x;
  const int wave = tid >> 6, lane = tid & 63;
  const int quad = lane >> 4, l16 = lane & 15;
  const int wm = (wave >> 1) * 64, wn = (wave & 1) * 64;

  f32x4 acc[4][4] = {};

  for (int k0 = 0; k0 < K; k0 += 32) {
    stage_tile(lAh, Ah + (size_t)m0 * lda + k0, lda, wave, lane);
    if (SPLIT) stage_tile(lAl, Al + (size_t)m0 * lda + k0, lda, wave, lane);
    stage_tile(lBh, Bh + (size_t)n0 * ldb + k0, ldb, wave, lane);
    if (SPLIT) stage_tile(lBl, Bl + (size_t)n0 * ldb + k0, ldb, wave, lane);
    __syncthreads();

    bf16x8 a_h[4], a_l[4], b_h[4], b_l[4];
#pragma unroll
    for (int i = 0; i < 4; ++i) {
      a_h[i] = ldsfrag(lAh, wm + i * 16 + l16, quad);
      b_h[i] = ldsfrag(lBh, wn + i * 16 + l16, quad);
      if (SPLIT) {
        a_l[i] = ldsfrag(lAl, wm + i * 16 + l16, quad);
        b_l[i] = ldsfrag(lBl, wn + i * 16 + l16, quad);
      }
    }
#pragma unroll
    for (int i = 0; i < 4; ++i)
#pragma unroll
      for (int j = 0; j < 4; ++j) {
        acc[i][j] = mfma16(a_h[i], b_h[j], acc[i][j]);
        if (SPLIT) {
          acc[i][j] = mfma16(a_h[i], b_l[j], acc[i][j]);
          acc[i][j] = mfma16(a_l[i], b_h[j], acc[i][j]);
        }
      }
    __syncthreads();
  }

#pragma unroll
  for (int i = 0; i < 4; ++i) {
#pragma unroll
    for (int j = 0; j < 4; ++j) {
      int col = n0 + wn + j * 16 + l16;
#pragma unroll
      for (int r = 0; r < 4; ++r) {
        int row = m0 + wm + i * 16 + quad * 4 + r;
        size_t idx = cOff + (size_t)row * ldc + col;
        float v = acc[i][j][r];
        if (OMODE == 0) {
          ((float*)C0)[idx] = v;
        } else if (OMODE == 1) {
          ((u16*)C0)[idx] = f2bf(v);
        } else {
          u16 h = f2bf(v);
          ((u16*)C0)[idx] = h;
          ((u16*)C1)[idx] = f2bf(v - bf2f(h));
        }
      }
    }
  }
}

// ---------------- GEMM core (256x256, 8 waves, 2-phase pipeline, R3) -------
__device__ __forceinline__ void stage256(u16* tile, const u16* g0, int ld,
                                         int tid) {
  const int wave = tid >> 6;
#pragma unroll
  for (int r = 0; r < 2; ++r) {
    int p = r * 512 + tid;                        // chunk index 0..1023
    int m = p >> 2;                               // row 0..255
    int cq = (p & 3) ^ ((m >> 1) & 3);            // global chunk col
    const u16* g = g0 + (size_t)m * ld + cq * 8;
    u16* l = tile + (size_t)(r * 512 + wave * 64) * 8;  // wave-uniform base
    __builtin_amdgcn_global_load_lds((gvoid_t*)g, (svoid_t*)l, 16, 0, 0);
  }
}

template <int SPLIT>
__device__ __forceinline__ void stage_all256(u16* buf, const u16* Ah,
                                             const u16* Al, const u16* Bh,
                                             const u16* Bl, int lda, int ldb,
                                             int m0, int n0, int k0, int tid) {
  stage256(buf, Ah + (size_t)m0 * lda + k0, lda, tid);
  if (SPLIT) stage256(buf + 8192, Al + (size_t)m0 * lda + k0, lda, tid);
  stage256(buf + (SPLIT ? 16384 : 8192), Bh + (size_t)n0 * ldb + k0, ldb, tid);
  if (SPLIT) stage256(buf + 24576, Bl + (size_t)n0 * ldb + k0, ldb, tid);
}

template <int SPLIT, int OMODE>
__global__ __launch_bounds__(512, 2) void gemm256(
    const u16* __restrict__ Ah, const u16* __restrict__ Al,
    const u16* __restrict__ Bh, const u16* __restrict__ Bl,
    void* __restrict__ C0, void* __restrict__ C1, int lda, int ldb, int ldc,
    int K, size_t aH, size_t aB, size_t bH, size_t bB, size_t cH, size_t cB) {
  constexpr int BUF = (SPLIT ? 4 : 2) * 8192;     // u16 per buffer
  __shared__ __align__(16) u16 lds[2 * BUF];

  const int gx = gridDim.x, gy = gridDim.y;
  const int nb = gx * gy * (int)gridDim.z;
  int orig = blockIdx.x + gx * (blockIdx.y + gy * blockIdx.z);
  int swz = orig;
  if ((nb & 7) == 0) swz = (orig & 7) * (nb >> 3) + (orig >> 3);
  const int bx = swz % gx;
  const int byz = swz / gx;
  const int by = byz % gy;
  const int bz = byz / gy;

  const int zh = bz >> 4, zb = bz & 15;
  Ah += zh * aH + zb * aB;
  Al += zh * aH + zb * aB;
  Bh += zh * bH + zb * bB;
  Bl += zh * bH + zb * bB;
  const size_t cOff = zh * cH + zb * cB;

  const int m0 = by * 256, n0 = bx * 256;
  const int tid = threadIdx.x;
  const int wave = tid >> 6, lane = tid & 63;
  const int quad = lane >> 4, l16 = lane & 15;
  const int wm = (wave >> 2) * 128, wn = (wave & 3) * 64;

  f32x4 acc[8][4] = {};

  stage_all256<SPLIT>(lds, Ah, Al, Bh, Bl, lda, ldb, m0, n0, 0, tid);
  __syncthreads();

  int cur = 0;
  for (int k0 = 0; k0 < K; k0 += 32) {
    if (k0 + 32 < K)
      stage_all256<SPLIT>(lds + (cur ^ 1) * BUF, Ah, Al, Bh, Bl, lda, ldb, m0,
                          n0, k0 + 32, tid);

    u16* lA_h = lds + cur * BUF;
    u16* lA_l = lA_h + 8192;
    u16* lB_h = lA_h + (SPLIT ? 16384 : 8192);
    u16* lB_l = lA_h + 24576;

    bf16x8 bhf[4], blf[4];
#pragma unroll
    for (int j = 0; j < 4; ++j) {
      bhf[j] = ldsfrag(lB_h, wn + j * 16 + l16, quad);
      if (SPLIT) blf[j] = ldsfrag(lB_l, wn + j * 16 + l16, quad);
    }
#pragma unroll
    for (int i = 0; i < 8; ++i) {
      bf16x8 ah = ldsfrag(lA_h, wm + i * 16 + l16, quad);
      bf16x8 al;
      if (SPLIT) al = ldsfrag(lA_l, wm + i * 16 + l16, quad);
#pragma unroll
      for (int j = 0; j < 4; ++j) {
        acc[i][j] = mfma16(ah, bhf[j], acc[i][j]);
        if (SPLIT) {
          acc[i][j] = mfma16(ah, blf[j], acc[i][j]);
          acc[i][j] = mfma16(al, bhf[j], acc[i][j]);
        }
      }
    }
    __syncthreads();
    cur ^= 1;
  }

#pragma unroll
  for (int i = 0; i < 8; ++i) {
#pragma unroll
    for (int j = 0; j < 4; ++j) {
      int col = n0 + wn + j * 16 + l16;
#pragma unroll
      for (int r = 0; r < 4; ++r) {
        int row = m0 + wm + i * 16 + quad * 4 + r;
        size_t idx = cOff + (size_t)row * ldc + col;
        float v = acc[i][j][r];
        if (OMODE == 0) {
          ((float*)C0)[idx] = v;
        } else if (OMODE == 1) {
          ((u16*)C0)[idx] = f2bf(v);
        } else {
          u16 h = f2bf(v);
          ((u16*)C0)[idx] = h;
          ((u16*)C1)[idx] = f2bf(v - bf2f(h));
        }
      }
    }
  }
}

// ---------------- fused logits + row-softmax -> P bf16 ---------------------
// Tile 128x512 (full softmax row per block), split x3 MFMA, BK=32, 512 thr.
// 8 waves = 1M x 8N: wave w covers cols w*64..w*64+64, all 128 rows;
// acc[8][4] (row = i*16+quad*4+r, col = w*64 + j*16 + l16).
// LDS/buffer: A(T) 128x32 hi/lo (8KB+8KB) + B(X_b) 512x32 hi/lo (32+32KB)
//   = 80KB; double-buffered = 160KB (full CU pool, 1 block/CU).
// Epilogue: strip max/sum over j + 16-lane shfl_xor; cross-wave via 4KB LDS
// scratch [row][8] (+2 barriers); P = exp(v-max)/sum written bf16 directly.
// Alias safety: P overwrites exactly the T-hi rows this block (alone) read.
__global__ __launch_bounds__(512, 2) void logits_sm(
    const u16* __restrict__ Th, const u16* __restrict__ Tl,
    const u16* __restrict__ Xh, const u16* __restrict__ Xl,
    u16* __restrict__ P, int lda, int ldb,
    size_t aH, size_t aB, size_t bB, size_t cH, size_t cB) {
  __shared__ __align__(16) u16 lds[81920];  // 2 x 40960 u16 = 160 KiB

  // bijective XCD swizzle (nb = 512, divisible by 8)
  const int gx = gridDim.x;  // 4 m-blocks
  const int nb = gx * (int)gridDim.y;
  int orig = blockIdx.x + gx * blockIdx.y;
  int swz = orig;
  if ((nb & 7) == 0) swz = (orig & 7) * (nb >> 3) + (orig >> 3);
  const int by = swz % gx;   // m-block
  const int bz = swz / gx;   // (h,b)

  const int zh = bz >> 4, zb = bz & 15;
  const u16* gA_h = Th + zh * aH + zb * aB;
  const u16* gA_l = Tl + zh * aH + zb * aB;
  const u16* gB_h = Xh + zb * bB;
  const u16* gB_l = Xl + zb * bB;
  const size_t cOff = zh * cH + zb * cB;

  const int m0 = by * 128;
  const int tid = threadIdx.x;
  const int wave = tid >> 6, lane = tid & 63;
  const int quad = lane >> 4, l16 = lane & 15;
  const int wn = wave * 64;

  const u16* A_h = gA_h + (size_t)m0 * lda;
  const u16* A_l = gA_l + (size_t)m0 * lda;

  f32x4 acc[8][4] = {};

  // stage one K-tile into buffer b: A 1 round, B 4 rounds (hi+lo each)
  auto STAGE = [&](int b, int kk) {
    u16* d = lds + b * 40960;
    {
      int m = tid >> 2;
      int cq = (tid & 3) ^ ((m >> 1) & 3);
      u16* l0 = d + (size_t)(wave * 64) * 8;
      __builtin_amdgcn_global_load_lds(
          (gvoid_t*)(A_h + (size_t)m * lda + kk + cq * 8), (svoid_t*)l0, 16, 0,
          0);
      __builtin_amdgcn_global_load_lds(
          (gvoid_t*)(A_l + (size_t)m * lda + kk + cq * 8),
          (svoid_t*)(l0 + 4096 * 8 / 8 + 0), 16, 0, 0);
    }
#pragma unroll
    for (int r = 0; r < 4; ++r) {
      int p = r * 512 + tid;
      int m = p >> 2;
      int cq = (p & 3) ^ ((m >> 1) & 3);
      u16* l0 = d + 8192 + (size_t)(r * 512 + wave * 64) * 8;
      __builtin_amdgcn_global_load_lds(
          (gvoid_t*)(gB_h + (size_t)m * ldb + kk + cq * 8), (svoid_t*)l0, 16,
          0, 0);
      __builtin_amdgcn_global_load_lds(
          (gvoid_t*)(gB_l + (size_t)m * ldb + kk + cq * 8),
          (svoid_t*)(l0 + 16384), 16, 0, 0);
    }
  };

  STAGE(0, 0);
  __syncthreads();

  int cur = 0;
  for (int t = 0; t < 16; ++t) {
    if (t + 1 < 16) STAGE(cur ^ 1, (t + 1) * 32);

    u16* buf = lds + cur * 40960;
    u16* lA_h = buf;
    u16* lA_l = buf + 4096;
    u16* lB_h = buf + 8192;
    u16* lB_l = buf + 24576;

    bf16x8 bhf[4], blf[4];
#pragma unroll
    for (int j = 0; j < 4; ++j) {
      bhf[j] = ldsfrag(lB_h, wn + j * 16 + l16, quad);
      blf[j] = ldsfrag(lB_l, wn + j * 16 + l16, quad);
    }
#pragma unroll
    for (int i = 0; i < 8; ++i) {
      bf16x8 ah = ldsfrag(lA_h, i * 16 + l16, quad);
      bf16x8 al = ldsfrag(lA_l, i * 16 + l16, quad);
#pragma unroll
      for (int j = 0; j < 4; ++j) {
        acc[i][j] = mfma16(ah, bhf[j], acc[i][j]);
        acc[i][j] = mfma16(ah, blf[j], acc[i][j]);
        acc[i][j] = mfma16(al, bhf[j], acc[i][j]);
      }
    }
    __syncthreads();
    cur ^= 1;
  }

  // ---- fused softmax epilogue ----
  float* smax = (float*)lds;           // [128][8] f32 = 4 KB
  float* ssum = (float*)(lds + 2048);  // [128][8] f32 = 4 KB (byte 4096)

  // phase 1: per-row strip max (this wave's 64 cols) -> LDS partials
#pragma unroll
  for (int i = 0; i < 8; ++i)
#pragma unroll
    for (int r = 0; r < 4; ++r) {
      float m = fmaxf(fmaxf(acc[i][0][r], acc[i][1][r]),
                      fmaxf(acc[i][2][r], acc[i][3][r]));
#pragma unroll
      for (int o = 1; o < 16; o <<= 1) m = fmaxf(m, __shfl_xor(m, o));
      if (l16 == 0) smax[(i * 16 + quad * 4 + r) * 8 + wave] = m;
    }
  __syncthreads();

  // phase 2: full row max, exp, strip sum -> LDS partials
#pragma unroll
  for (int i = 0; i < 8; ++i)
#pragma unroll
    for (int r = 0; r < 4; ++r) {
      int row = i * 16 + quad * 4 + r;
      f32x4 a = *(f32x4*)&smax[row * 8];
      f32x4 b = *(f32x4*)&smax[row * 8 + 4];
      float m = fmaxf(fmaxf(fmaxf(a[0], a[1]), fmaxf(a[2], a[3])),
                      fmaxf(fmaxf(b[0], b[1]), fmaxf(b[2], b[3])));
      float s = 0.f;
#pragma unroll
      for (int j = 0; j < 4; ++j) {
        float e = __expf(acc[i][j][r] - m);
        acc[i][j][r] = e;
        s += e;
      }
#pragma unroll
      for (int o = 1; o < 16; o <<= 1) s += __shfl_xor(s, o);
      if (l16 == 0) ssum[row * 8 + wave] = s;
    }
  __syncthreads();

  // phase 3: normalize + write P bf16
#pragma unroll
  for (int i = 0; i < 8; ++i)
#pragma unroll
    for (int r = 0; r < 4; ++r) {
      int row = i * 16 + quad * 4 + r;
      f32x4 a = *(f32x4*)&ssum[row * 8];
      f32x4 b = *(f32x4*)&ssum[row * 8 + 4];
      float s = (a[0] + a[1]) + (a[2] + a[3]) + (b[0] + b[1]) + (b[2] + b[3]);
      float inv = 1.0f / s;
      size_t base = cOff + (size_t)(m0 + row) * 512;
#pragma unroll
      for (int j = 0; j < 4; ++j)
        P[base + wn + j * 16 + l16] = f2bf(acc[i][j][r] * inv);
    }
}

// ---------------------------------------------------------------------------
extern "C" void kernel_launch(void* const* d_in, const int* in_sizes, int n_in,
                              void* d_out, int out_size, void* d_ws,
                              size_t ws_size, hipStream_t stream) {
  const float* x = (const float*)d_in[0];   // [16,512,512]  = [8192,512]
  const float* wq = (const float*)d_in[1];  // [512,4096]
  const float* wk = (const float*)d_in[2];
  const float* wv = (const float*)d_in[3];
  float* out = (float*)d_out;               // [16,512,4096]
  char* ws = (char*)d_ws;

  const size_t MB = 1024ull * 1024ull;
  u16* XHI = (u16*)(ws + 0 * MB);    // [8192,512] bf16 hi      8MB
  u16* XLO = (u16*)(ws + 8 * MB);    //                         8MB
  u16* WQH = (u16*)(ws + 16 * MB);   // wq split, orig layout   4MB
  u16* WQL = (u16*)(ws + 20 * MB);
  u16* WKH = (u16*)(ws + 24 * MB);
  u16* WKL = (u16*)(ws + 28 * MB);
  u16* WVTH = (u16*)(ws + 32 * MB);  // wv^T [4096,512]         4MB
  u16* WVTL = (u16*)(ws + 36 * MB);
  u16* MPH = (u16*)(ws + 40 * MB);   // M' = Wk Wq^T [8,512,512] 4MB
  u16* MPL = (u16*)(ws + 44 * MB);
  u16* THI = (u16*)(ws + 48 * MB);   // T = X M'^T [8,8192,512] 64MB
  u16* TLO = (u16*)(ws + 112 * MB);  //                         64MB
  u16* VT = (u16*)(ws + 176 * MB);   // V^T [4096,8192] bf16    64MB
  u16* P = THI;                      // probs alias T-hi (row-safe in-place)

  // --- prep ---
  split_hl_kernel<<<4096, 256, 0, stream>>>(x, XHI, XLO, 1048576);
  split_hl_kernel<<<2048, 256, 0, stream>>>(wq, WQH, WQL, 524288);
  split_hl_kernel<<<2048, 256, 0, stream>>>(wk, WKH, WKL, 524288);
  transpose_split_w<<<dim3(128, 16), dim3(32, 8), 0, stream>>>(wv, WVTH, WVTL);

  // --- M'_h = Wk_h Wq_h^T : [512,512] per head, x3 split, hi/lo out ---
  gemm_bt<1, 2><<<dim3(4, 4, 8), 256, 0, stream>>>(
      WKH, WKL, WQH, WQL, MPH, MPL, 4096, 4096, 512, 512,
      /*aH*/ 0, /*aB*/ 512, /*bH*/ 0, /*bB*/ 512, /*cH*/ 0, /*cB*/ 262144);

  // --- T_h = X M'_h^T : [8192,512] per head, x3, hi/lo out ---
  gemm256<1, 2><<<dim3(2, 32, 8), 512, 0, stream>>>(
      XHI, XLO, MPH, MPL, THI, TLO, 512, 512, 512, 512,
      0, 0, 0, 262144, 0, 4194304);

  // --- V^T = Wv^T X^T : [4096 d, 8192 s], plain bf16 ---
  gemm256<0, 1><<<dim3(32, 16, 1), 512, 0, stream>>>(
      WVTH, WVTH, XHI, XHI, VT, nullptr, 512, 512, 8192, 512,
      0, 0, 0, 0, 0, 0);

  // --- P_hb = softmax(T_h[b] X[b]^T) : fused, bf16 out (in-place on THI) ---
  logits_sm<<<dim3(4, 128), 512, 0, stream>>>(
      THI, TLO, XHI, XLO, P, 512, 512,
      /*aH*/ 4194304, /*aB*/ 262144, /*bB*/ 262144,
      /*cH*/ 4194304, /*cB*/ 262144);

  // --- out_hb = P_hb V_hb : [512 q, 512 d], plain bf16 -> fp32 out,
  //     written interleaved: out[(b*512+q)*4096 + h*512 + d] ---
  gemm256<0, 0><<<dim3(2, 2, 128), 512, 0, stream>>>(
      P, P, VT, VT, out, nullptr, 512, 8192, 4096, 512,
      /*aH*/ 4194304, /*aB*/ 262144, /*bH*/ 4194304, /*bB*/ 512,
      /*cH*/ 512, /*cB*/ 2097152);
}

// Round 9
// 496.185 us; speedup vs baseline: 4.3631x; 1.0058x over previous
//
#include <hip/hip_runtime.h>

// ---------------------------------------------------------------------------
// MultiHead_BlockAttention: out[b,s,h*512+d] = softmax(Q Kt) V  per (h,b)
//   Q = x@wq, K = x@wk, V = x@wv ; head h = cols [h*512,(h+1)*512)
// Trick: logits = X (Wq Wk^T) X^T  -> precompute M' = Wk Wq^T per head.
// Precision: bf16 hi/lo split (3 MFMAs) on the logit path; plain bf16 for V/P.
// R3: all big GEMMs on gemm256 (256x256, 8 waves, dbuf, 2-phase). 513us.
// R4/R5/R7 schedule tweaks: null -> split-GEMM K-step at structural ceiling.
// R8: softmax fused into logits GEMM (128x512 tile, P bf16 direct). 499us.
// R9: PV fused in as well. After softmax, P (128x512 bf16 = 128KB) goes to
//     LDS (16 chunk-swizzled K-tiles) instead of HBM; V streamed in 32KB
//     tiles with reg-staged T14 prefetch; out written directly. Eliminates
//     P write/read + the PV dispatch. LDS = 160KB exactly.
// ---------------------------------------------------------------------------

typedef unsigned short u16;
typedef __bf16 bf16x8 __attribute__((ext_vector_type(8)));
typedef unsigned short u16x4 __attribute__((ext_vector_type(4)));
typedef unsigned short u16x8s __attribute__((ext_vector_type(8)));
typedef float f32x4 __attribute__((ext_vector_type(4)));

typedef __attribute__((address_space(1))) void gvoid_t;
typedef __attribute__((address_space(3))) void svoid_t;

__device__ __forceinline__ u16 f2bf(float f) {
  unsigned u = __float_as_uint(f);
  u = (u + 0x7fffu + ((u >> 16) & 1u)) >> 16;  // RTN-even
  return (u16)u;
}
__device__ __forceinline__ float bf2f(u16 h) {
  return __uint_as_float(((unsigned)h) << 16);
}

__device__ __forceinline__ f32x4 mfma16(bf16x8 a, bf16x8 b, f32x4 c) {
  return __builtin_amdgcn_mfma_f32_16x16x32_bf16(a, b, c, 0, 0, 0);
}

// ---------------- prep: fp32 -> bf16 hi/lo split (same layout) -------------
__global__ __launch_bounds__(256) void split_hl_kernel(
    const float* __restrict__ in, u16* __restrict__ hi, u16* __restrict__ lo,
    int n4) {
  int i = blockIdx.x * 256 + threadIdx.x;
  if (i >= n4) return;
  float4 v = ((const float4*)in)[i];
  float vv[4] = {v.x, v.y, v.z, v.w};
  u16x4 h, l;
#pragma unroll
  for (int j = 0; j < 4; ++j) {
    u16 hh = f2bf(vv[j]);
    h[j] = hh;
    l[j] = f2bf(vv[j] - bf2f(hh));
  }
  ((u16x4*)hi)[i] = h;
  ((u16x4*)lo)[i] = l;
}

// ---------------- prep: transpose [512,4096] -> [4096,512] + split ---------
__global__ __launch_bounds__(256) void transpose_split_w(
    const float* __restrict__ in, u16* __restrict__ hi, u16* __restrict__ lo) {
  __shared__ float t[32][33];
  int d0 = blockIdx.x * 32, f0 = blockIdx.y * 32;
  int tx = threadIdx.x, ty = threadIdx.y;  // blockDim = (32,8)
#pragma unroll
  for (int r = 0; r < 4; ++r)
    t[ty + r * 8][tx] = in[(size_t)(f0 + ty + r * 8) * 4096 + d0 + tx];
  __syncthreads();
#pragma unroll
  for (int r = 0; r < 4; ++r) {
    float v = t[tx][ty + r * 8];  // = in[f0+tx][d0+ty+r*8]
    int d = d0 + ty + r * 8, f = f0 + tx;
    u16 h = f2bf(v);
    size_t idx = (size_t)d * 512 + f;
    hi[idx] = h;
    lo[idx] = f2bf(v - bf2f(h));
  }
}

// ---------------- shared LDS swizzle helpers -------------------------------
// LDS tiles [rows][32 k] bf16, XOR-swizzled at 16B-chunk granularity:
//   chunk (m,cq) stored at chunk col c' = cq ^ ((m>>1)&3)  (involution)
__device__ __forceinline__ bf16x8 ldsfrag(const u16* tile, int row, int quad) {
  int c = quad ^ ((row >> 1) & 3);
  return *(const bf16x8*)(tile + row * 32 + c * 8);
}

// ---------------- GEMM core (legacy 128x128) -------------------------------
__device__ __forceinline__ void stage_tile(u16* ldsTile, const u16* g0, int ld,
                                           int wave, int lane) {
#pragma unroll
  for (int r = 0; r < 2; ++r) {
    int p = r * 256 + wave * 64 + lane;          // LDS chunk position
    int m = p >> 2;
    int cq = (p & 3) ^ ((m >> 1) & 3);           // global chunk col
    const u16* g = g0 + (size_t)m * ld + cq * 8;
    u16* l = ldsTile + (size_t)(r * 256 + wave * 64) * 8;  // wave-uniform
    __builtin_amdgcn_global_load_lds((gvoid_t*)g, (svoid_t*)l, 16, 0, 0);
  }
}

// OMODE: 0 = fp32 to C0 ; 1 = bf16 to C0 ; 2 = hi/lo bf16 to C0/C1
template <int SPLIT, int OMODE>
__global__ __launch_bounds__(256, 2) void gemm_bt(
    const u16* __restrict__ Ah, const u16* __restrict__ Al,
    const u16* __restrict__ Bh, const u16* __restrict__ Bl,
    void* __restrict__ C0, void* __restrict__ C1, int lda, int ldb, int ldc,
    int K, size_t aH, size_t aB, size_t bH, size_t bB, size_t cH, size_t cB) {
  __shared__ __align__(16) u16 lds[(SPLIT ? 4 : 2) * 4096];
  u16* lAh = lds;
  u16* lAl = SPLIT ? (lds + 4096) : lds;
  u16* lBh = lds + (SPLIT ? 8192 : 4096);
  u16* lBl = SPLIT ? (lds + 12288) : lds;

  const int zh = blockIdx.z >> 4, zb = blockIdx.z & 15;
  Ah += zh * aH + zb * aB;
  Al += zh * aH + zb * aB;
  Bh += zh * bH + zb * bB;
  Bl += zh * bH + zb * bB;
  const size_t cOff = zh * cH + zb * cB;

  const int m0 = blockIdx.y * 128, n0 = blockIdx.x * 128;
  const int tid = threadIdx.x;
  const int wave = tid >> 6, lane = tid & 63;
  const int quad = lane >> 4, l16 = lane & 15;
  const int wm = (wave >> 1) * 64, wn = (wave & 1) * 64;

  f32x4 acc[4][4] = {};

  for (int k0 = 0; k0 < K; k0 += 32) {
    stage_tile(lAh, Ah + (size_t)m0 * lda + k0, lda, wave, lane);
    if (SPLIT) stage_tile(lAl, Al + (size_t)m0 * lda + k0, lda, wave, lane);
    stage_tile(lBh, Bh + (size_t)n0 * ldb + k0, ldb, wave, lane);
    if (SPLIT) stage_tile(lBl, Bl + (size_t)n0 * ldb + k0, ldb, wave, lane);
    __syncthreads();

    bf16x8 a_h[4], a_l[4], b_h[4], b_l[4];
#pragma unroll
    for (int i = 0; i < 4; ++i) {
      a_h[i] = ldsfrag(lAh, wm + i * 16 + l16, quad);
      b_h[i] = ldsfrag(lBh, wn + i * 16 + l16, quad);
      if (SPLIT) {
        a_l[i] = ldsfrag(lAl, wm + i * 16 + l16, quad);
        b_l[i] = ldsfrag(lBl, wn + i * 16 + l16, quad);
      }
    }
#pragma unroll
    for (int i = 0; i < 4; ++i)
#pragma unroll
      for (int j = 0; j < 4; ++j) {
        acc[i][j] = mfma16(a_h[i], b_h[j], acc[i][j]);
        if (SPLIT) {
          acc[i][j] = mfma16(a_h[i], b_l[j], acc[i][j]);
          acc[i][j] = mfma16(a_l[i], b_h[j], acc[i][j]);
        }
      }
    __syncthreads();
  }

#pragma unroll
  for (int i = 0; i < 4; ++i) {
#pragma unroll
    for (int j = 0; j < 4; ++j) {
      int col = n0 + wn + j * 16 + l16;
#pragma unroll
      for (int r = 0; r < 4; ++r) {
        int row = m0 + wm + i * 16 + quad * 4 + r;
        size_t idx = cOff + (size_t)row * ldc + col;
        float v = acc[i][j][r];
        if (OMODE == 0) {
          ((float*)C0)[idx] = v;
        } else if (OMODE == 1) {
          ((u16*)C0)[idx] = f2bf(v);
        } else {
          u16 h = f2bf(v);
          ((u16*)C0)[idx] = h;
          ((u16*)C1)[idx] = f2bf(v - bf2f(h));
        }
      }
    }
  }
}

// ---------------- GEMM core (256x256, 8 waves, 2-phase pipeline, R3) -------
__device__ __forceinline__ void stage256(u16* tile, const u16* g0, int ld,
                                         int tid) {
  const int wave = tid >> 6;
#pragma unroll
  for (int r = 0; r < 2; ++r) {
    int p = r * 512 + tid;                        // chunk index 0..1023
    int m = p >> 2;                               // row 0..255
    int cq = (p & 3) ^ ((m >> 1) & 3);            // global chunk col
    const u16* g = g0 + (size_t)m * ld + cq * 8;
    u16* l = tile + (size_t)(r * 512 + wave * 64) * 8;  // wave-uniform base
    __builtin_amdgcn_global_load_lds((gvoid_t*)g, (svoid_t*)l, 16, 0, 0);
  }
}

template <int SPLIT>
__device__ __forceinline__ void stage_all256(u16* buf, const u16* Ah,
                                             const u16* Al, const u16* Bh,
                                             const u16* Bl, int lda, int ldb,
                                             int m0, int n0, int k0, int tid) {
  stage256(buf, Ah + (size_t)m0 * lda + k0, lda, tid);
  if (SPLIT) stage256(buf + 8192, Al + (size_t)m0 * lda + k0, lda, tid);
  stage256(buf + (SPLIT ? 16384 : 8192), Bh + (size_t)n0 * ldb + k0, ldb, tid);
  if (SPLIT) stage256(buf + 24576, Bl + (size_t)n0 * ldb + k0, ldb, tid);
}

template <int SPLIT, int OMODE>
__global__ __launch_bounds__(512, 2) void gemm256(
    const u16* __restrict__ Ah, const u16* __restrict__ Al,
    const u16* __restrict__ Bh, const u16* __restrict__ Bl,
    void* __restrict__ C0, void* __restrict__ C1, int lda, int ldb, int ldc,
    int K, size_t aH, size_t aB, size_t bH, size_t bB, size_t cH, size_t cB) {
  constexpr int BUF = (SPLIT ? 4 : 2) * 8192;     // u16 per buffer
  __shared__ __align__(16) u16 lds[2 * BUF];

  const int gx = gridDim.x, gy = gridDim.y;
  const int nb = gx * gy * (int)gridDim.z;
  int orig = blockIdx.x + gx * (blockIdx.y + gy * blockIdx.z);
  int swz = orig;
  if ((nb & 7) == 0) swz = (orig & 7) * (nb >> 3) + (orig >> 3);
  const int bx = swz % gx;
  const int byz = swz / gx;
  const int by = byz % gy;
  const int bz = byz / gy;

  const int zh = bz >> 4, zb = bz & 15;
  Ah += zh * aH + zb * aB;
  Al += zh * aH + zb * aB;
  Bh += zh * bH + zb * bB;
  Bl += zh * bH + zb * bB;
  const size_t cOff = zh * cH + zb * cB;

  const int m0 = by * 256, n0 = bx * 256;
  const int tid = threadIdx.x;
  const int wave = tid >> 6, lane = tid & 63;
  const int quad = lane >> 4, l16 = lane & 15;
  const int wm = (wave >> 2) * 128, wn = (wave & 3) * 64;

  f32x4 acc[8][4] = {};

  stage_all256<SPLIT>(lds, Ah, Al, Bh, Bl, lda, ldb, m0, n0, 0, tid);
  __syncthreads();

  int cur = 0;
  for (int k0 = 0; k0 < K; k0 += 32) {
    if (k0 + 32 < K)
      stage_all256<SPLIT>(lds + (cur ^ 1) * BUF, Ah, Al, Bh, Bl, lda, ldb, m0,
                          n0, k0 + 32, tid);

    u16* lA_h = lds + cur * BUF;
    u16* lA_l = lA_h + 8192;
    u16* lB_h = lA_h + (SPLIT ? 16384 : 8192);
    u16* lB_l = lA_h + 24576;

    bf16x8 bhf[4], blf[4];
#pragma unroll
    for (int j = 0; j < 4; ++j) {
      bhf[j] = ldsfrag(lB_h, wn + j * 16 + l16, quad);
      if (SPLIT) blf[j] = ldsfrag(lB_l, wn + j * 16 + l16, quad);
    }
#pragma unroll
    for (int i = 0; i < 8; ++i) {
      bf16x8 ah = ldsfrag(lA_h, wm + i * 16 + l16, quad);
      bf16x8 al;
      if (SPLIT) al = ldsfrag(lA_l, wm + i * 16 + l16, quad);
#pragma unroll
      for (int j = 0; j < 4; ++j) {
        acc[i][j] = mfma16(ah, bhf[j], acc[i][j]);
        if (SPLIT) {
          acc[i][j] = mfma16(ah, blf[j], acc[i][j]);
          acc[i][j] = mfma16(al, bhf[j], acc[i][j]);
        }
      }
    }
    __syncthreads();
    cur ^= 1;
  }

#pragma unroll
  for (int i = 0; i < 8; ++i) {
#pragma unroll
    for (int j = 0; j < 4; ++j) {
      int col = n0 + wn + j * 16 + l16;
#pragma unroll
      for (int r = 0; r < 4; ++r) {
        int row = m0 + wm + i * 16 + quad * 4 + r;
        size_t idx = cOff + (size_t)row * ldc + col;
        float v = acc[i][j][r];
        if (OMODE == 0) {
          ((float*)C0)[idx] = v;
        } else if (OMODE == 1) {
          ((u16*)C0)[idx] = f2bf(v);
        } else {
          u16 h = f2bf(v);
          ((u16*)C0)[idx] = h;
          ((u16*)C1)[idx] = f2bf(v - bf2f(h));
        }
      }
    }
  }
}

// ---------------- fused logits + softmax + PV -> out ----------------------
// Tile 128x512 (full softmax row per block), split x3 MFMA, BK=32, 512 thr.
// 8 waves = 1M x 8N; acc[8][4]: row = i*16+quad*4+r, col = wave*64+j*16+l16.
// Main loop LDS: dbuf 2 x 40960 u16 = 160KB (A=T 128x32 hi/lo, B=X 512x32
// hi/lo). After softmax: LDS repurposed to P (16 chunk-swizzled K-tiles of
// [128][32] bf16 = 128KB) + V tile buffer (512x32 bf16 = 32KB) = 160KB.
// PV: out_rows = P(128x512) @ V(512x512); V^T rows streamed from VT with
// reg-staged prefetch (T14): loads for t+1 issued before compute t.
__global__ __launch_bounds__(512, 2) void logits_sm_pv(
    const u16* __restrict__ Th, const u16* __restrict__ Tl,
    const u16* __restrict__ Xh, const u16* __restrict__ Xl,
    const u16* __restrict__ VT, float* __restrict__ out,
    size_t aH, size_t aB, size_t bB) {
  __shared__ __align__(16) u16 lds[81920];  // 160 KiB

  // bijective XCD swizzle (nb = 512, divisible by 8)
  const int gx = gridDim.x;  // 4 m-blocks
  const int nb = gx * (int)gridDim.y;
  int orig = blockIdx.x + gx * blockIdx.y;
  int swz = orig;
  if ((nb & 7) == 0) swz = (orig & 7) * (nb >> 3) + (orig >> 3);
  const int by = swz % gx;   // m-block
  const int bz = swz / gx;   // (h,b)

  const int zh = bz >> 4, zb = bz & 15;
  const u16* gA_h = Th + zh * aH + zb * aB;
  const u16* gA_l = Tl + zh * aH + zb * aB;
  const u16* gB_h = Xh + zb * bB;
  const u16* gB_l = Xl + zb * bB;
  const u16* gV = VT + (size_t)zh * 512 * 8192 + (size_t)zb * 512;

  const int m0 = by * 128;
  const int tid = threadIdx.x;
  const int wave = tid >> 6, lane = tid & 63;
  const int quad = lane >> 4, l16 = lane & 15;
  const int wn = wave * 64;
  const int lda = 512, ldb = 512;

  const u16* A_h = gA_h + (size_t)m0 * lda;
  const u16* A_l = gA_l + (size_t)m0 * lda;

  f32x4 acc[8][4] = {};

  // stage one K-tile into buffer b: A 1 round, B 4 rounds (hi+lo each)
  auto STAGE = [&](int b, int kk) {
    u16* d = lds + b * 40960;
    {
      int m = tid >> 2;
      int cq = (tid & 3) ^ ((m >> 1) & 3);
      u16* l0 = d + (size_t)(wave * 64) * 8;
      __builtin_amdgcn_global_load_lds(
          (gvoid_t*)(A_h + (size_t)m * lda + kk + cq * 8), (svoid_t*)l0, 16, 0,
          0);
      __builtin_amdgcn_global_load_lds(
          (gvoid_t*)(A_l + (size_t)m * lda + kk + cq * 8),
          (svoid_t*)(l0 + 4096), 16, 0, 0);
    }
#pragma unroll
    for (int r = 0; r < 4; ++r) {
      int p = r * 512 + tid;
      int m = p >> 2;
      int cq = (p & 3) ^ ((m >> 1) & 3);
      u16* l0 = d + 8192 + (size_t)(r * 512 + wave * 64) * 8;
      __builtin_amdgcn_global_load_lds(
          (gvoid_t*)(gB_h + (size_t)m * ldb + kk + cq * 8), (svoid_t*)l0, 16,
          0, 0);
      __builtin_amdgcn_global_load_lds(
          (gvoid_t*)(gB_l + (size_t)m * ldb + kk + cq * 8),
          (svoid_t*)(l0 + 16384), 16, 0, 0);
    }
  };

  STAGE(0, 0);
  __syncthreads();

  int cur = 0;
  for (int t = 0; t < 16; ++t) {
    if (t + 1 < 16) STAGE(cur ^ 1, (t + 1) * 32);

    u16* buf = lds + cur * 40960;
    u16* lA_h = buf;
    u16* lA_l = buf + 4096;
    u16* lB_h = buf + 8192;
    u16* lB_l = buf + 24576;

    bf16x8 bhf[4], blf[4];
#pragma unroll
    for (int j = 0; j < 4; ++j) {
      bhf[j] = ldsfrag(lB_h, wn + j * 16 + l16, quad);
      blf[j] = ldsfrag(lB_l, wn + j * 16 + l16, quad);
    }
#pragma unroll
    for (int i = 0; i < 8; ++i) {
      bf16x8 ah = ldsfrag(lA_h, i * 16 + l16, quad);
      bf16x8 al = ldsfrag(lA_l, i * 16 + l16, quad);
#pragma unroll
      for (int j = 0; j < 4; ++j) {
        acc[i][j] = mfma16(ah, bhf[j], acc[i][j]);
        acc[i][j] = mfma16(ah, blf[j], acc[i][j]);
        acc[i][j] = mfma16(al, bhf[j], acc[i][j]);
      }
    }
    __syncthreads();
    cur ^= 1;
  }

  // ---- softmax (normalize acc in place) ----
  float* smax = (float*)lds;           // [128][8] f32 = 4 KB
  float* ssum = (float*)(lds + 2048);  // [128][8] f32 = 4 KB

#pragma unroll
  for (int i = 0; i < 8; ++i)
#pragma unroll
    for (int r = 0; r < 4; ++r) {
      float m = fmaxf(fmaxf(acc[i][0][r], acc[i][1][r]),
                      fmaxf(acc[i][2][r], acc[i][3][r]));
#pragma unroll
      for (int o = 1; o < 16; o <<= 1) m = fmaxf(m, __shfl_xor(m, o));
      if (l16 == 0) smax[(i * 16 + quad * 4 + r) * 8 + wave] = m;
    }
  __syncthreads();

#pragma unroll
  for (int i = 0; i < 8; ++i)
#pragma unroll
    for (int r = 0; r < 4; ++r) {
      int row = i * 16 + quad * 4 + r;
      f32x4 a = *(f32x4*)&smax[row * 8];
      f32x4 b = *(f32x4*)&smax[row * 8 + 4];
      float m = fmaxf(fmaxf(fmaxf(a[0], a[1]), fmaxf(a[2], a[3])),
                      fmaxf(fmaxf(b[0], b[1]), fmaxf(b[2], b[3])));
      float s = 0.f;
#pragma unroll
      for (int j = 0; j < 4; ++j) {
        float e = __expf(acc[i][j][r] - m);
        acc[i][j][r] = e;
        s += e;
      }
#pragma unroll
      for (int o = 1; o < 16; o <<= 1) s += __shfl_xor(s, o);
      if (l16 == 0) ssum[row * 8 + wave] = s;
    }
  __syncthreads();

#pragma unroll
  for (int i = 0; i < 8; ++i)
#pragma unroll
    for (int r = 0; r < 4; ++r) {
      int row = i * 16 + quad * 4 + r;
      f32x4 a = *(f32x4*)&ssum[row * 8];
      f32x4 b = *(f32x4*)&ssum[row * 8 + 4];
      float s = (a[0] + a[1]) + (a[2] + a[3]) + (b[0] + b[1]) + (b[2] + b[3]);
      float inv = 1.0f / s;
#pragma unroll
      for (int j = 0; j < 4; ++j) acc[i][j][r] *= inv;
    }
  __syncthreads();  // all scratch reads done; P region may be overwritten

  // ---- write P to LDS as 16 chunk-swizzled K-tiles [128][32] bf16 ----
  u16* Plds = lds;               // 65536 u16 = 128 KB
  u16* Vbuf = lds + 65536;       // 16384 u16 = 32 KB

  // V prefetch (tile 0) to registers while P writes happen
  u16x8s vreg[4];
  auto VLOAD = [&](int kk) {
#pragma unroll
    for (int r = 0; r < 4; ++r) {
      int p = r * 512 + tid;
      int m = p >> 2;
      int cq = (p & 3) ^ ((m >> 1) & 3);
      vreg[r] = *(const u16x8s*)(gV + (size_t)m * 8192 + kk + cq * 8);
    }
  };
  VLOAD(0);

#pragma unroll
  for (int i = 0; i < 8; ++i)
#pragma unroll
    for (int j = 0; j < 4; ++j)
#pragma unroll
      for (int r = 0; r < 4; ++r) {
        int row = i * 16 + quad * 4 + r;
        int col = wn + j * 16 + l16;
        int t = col >> 5, c = col & 31;
        int cp = (c >> 3) ^ ((row >> 1) & 3);
        Plds[t * 4096 + row * 32 + cp * 8 + (c & 7)] = f2bf(acc[i][j][r]);
      }
  __syncthreads();  // P visible to all

  // ---- PV: out_rows(128x512) = P @ V, V^T rows streamed 32-k per step ----
  f32x4 acc2[8][4] = {};
  for (int t = 0; t < 16; ++t) {
    // write prefetched V tile, then issue next tile's loads
#pragma unroll
    for (int r = 0; r < 4; ++r)
      *(u16x8s*)(Vbuf + (size_t)(r * 512 + tid) * 8) = vreg[r];
    if (t + 1 < 16) VLOAD((t + 1) * 32);
    __syncthreads();  // Vbuf ready

    const u16* Pt = Plds + t * 4096;
    bf16x8 bhf[4];
#pragma unroll
    for (int j = 0; j < 4; ++j)
      bhf[j] = ldsfrag(Vbuf, wn + j * 16 + l16, quad);
#pragma unroll
    for (int i = 0; i < 8; ++i) {
      bf16x8 pa = ldsfrag(Pt, i * 16 + l16, quad);
#pragma unroll
      for (int j = 0; j < 4; ++j) acc2[i][j] = mfma16(pa, bhf[j], acc2[i][j]);
    }
    __syncthreads();  // all reads of Vbuf done before next overwrite
  }

  // ---- out write: out[(zb*512 + m0+row)*4096 + zh*512 + col] fp32 ----
  const size_t oBase = ((size_t)zb * 512 + m0) * 4096 + (size_t)zh * 512;
#pragma unroll
  for (int i = 0; i < 8; ++i)
#pragma unroll
    for (int j = 0; j < 4; ++j) {
      int col = wn + j * 16 + l16;
#pragma unroll
      for (int r = 0; r < 4; ++r) {
        int row = i * 16 + quad * 4 + r;
        out[oBase + (size_t)row * 4096 + col] = acc2[i][j][r];
      }
    }
}

// ---------------------------------------------------------------------------
extern "C" void kernel_launch(void* const* d_in, const int* in_sizes, int n_in,
                              void* d_out, int out_size, void* d_ws,
                              size_t ws_size, hipStream_t stream) {
  const float* x = (const float*)d_in[0];   // [16,512,512]  = [8192,512]
  const float* wq = (const float*)d_in[1];  // [512,4096]
  const float* wk = (const float*)d_in[2];
  const float* wv = (const float*)d_in[3];
  float* out = (float*)d_out;               // [16,512,4096]
  char* ws = (char*)d_ws;

  const size_t MB = 1024ull * 1024ull;
  u16* XHI = (u16*)(ws + 0 * MB);    // [8192,512] bf16 hi      8MB
  u16* XLO = (u16*)(ws + 8 * MB);    //                         8MB
  u16* WQH = (u16*)(ws + 16 * MB);   // wq split, orig layout   4MB
  u16* WQL = (u16*)(ws + 20 * MB);
  u16* WKH = (u16*)(ws + 24 * MB);
  u16* WKL = (u16*)(ws + 28 * MB);
  u16* WVTH = (u16*)(ws + 32 * MB);  // wv^T [4096,512]         4MB
  u16* WVTL = (u16*)(ws + 36 * MB);
  u16* MPH = (u16*)(ws + 40 * MB);   // M' = Wk Wq^T [8,512,512] 4MB
  u16* MPL = (u16*)(ws + 44 * MB);
  u16* THI = (u16*)(ws + 48 * MB);   // T = X M'^T [8,8192,512] 64MB
  u16* TLO = (u16*)(ws + 112 * MB);  //                         64MB
  u16* VT = (u16*)(ws + 176 * MB);   // V^T [4096,8192] bf16    64MB

  // --- prep ---
  split_hl_kernel<<<4096, 256, 0, stream>>>(x, XHI, XLO, 1048576);
  split_hl_kernel<<<2048, 256, 0, stream>>>(wq, WQH, WQL, 524288);
  split_hl_kernel<<<2048, 256, 0, stream>>>(wk, WKH, WKL, 524288);
  transpose_split_w<<<dim3(128, 16), dim3(32, 8), 0, stream>>>(wv, WVTH, WVTL);

  // --- M'_h = Wk_h Wq_h^T : [512,512] per head, x3 split, hi/lo out ---
  gemm_bt<1, 2><<<dim3(4, 4, 8), 256, 0, stream>>>(
      WKH, WKL, WQH, WQL, MPH, MPL, 4096, 4096, 512, 512,
      /*aH*/ 0, /*aB*/ 512, /*bH*/ 0, /*bB*/ 512, /*cH*/ 0, /*cB*/ 262144);

  // --- T_h = X M'_h^T : [8192,512] per head, x3, hi/lo out ---
  gemm256<1, 2><<<dim3(2, 32, 8), 512, 0, stream>>>(
      XHI, XLO, MPH, MPL, THI, TLO, 512, 512, 512, 512,
      0, 0, 0, 262144, 0, 4194304);

  // --- V^T = Wv^T X^T : [4096 d, 8192 s], plain bf16 ---
  gemm256<0, 1><<<dim3(32, 16, 1), 512, 0, stream>>>(
      WVTH, WVTH, XHI, XHI, VT, nullptr, 512, 512, 8192, 512,
      0, 0, 0, 0, 0, 0);

  // --- out rows = softmax(T_h[b] X[b]^T) V_hb : fully fused ---
  logits_sm_pv<<<dim3(4, 128), 512, 0, stream>>>(
      THI, TLO, XHI, XLO, VT, out,
      /*aH*/ 4194304, /*aB*/ 262144, /*bB*/ 262144);
}